// Round 4
// baseline (245.716 us; speedup 1.0000x reference)
//
#include <hip/hip_runtime.h>

typedef __attribute__((ext_vector_type(8))) __bf16 bf16x8;
typedef __attribute__((ext_vector_type(4))) float f32x4;

#define DEVINL __device__ __forceinline__

constexpr int BZ = 4;
constexpr int SEQ = 1024;
constexpr int DMODEL = 1024;
constexpr int NH = 16;
constexpr int HD = 64;               // dk = dv = 64
constexpr int MSLOT = 128;
constexpr int NT = BZ * SEQ;         // 4096 tokens
constexpr int SKM = SEQ + MSLOT;     // 1152 keys per batch
constexpr int VT_LD = BZ * SKM;      // 4608: leading dim of global V^T
constexpr float SCALE_M = 11.313708498984761f;   // sqrt(128)
constexpr float SCEXP = 0.18033688011112042f;    // (1/sqrt(dk)) * log2(e)
// workspace offsets in bf16 (ushort) elements
constexpr size_t OF_QIN  = 0;
constexpr size_t OF_KIN  = OF_QIN  + (size_t)NT * DMODEL;
constexpr size_t OF_VIN  = OF_KIN  + (size_t)NT * DMODEL;
constexpr size_t OF_WQT  = OF_VIN  + (size_t)NT * DMODEL;
constexpr size_t OF_WKT  = OF_WQT  + (size_t)DMODEL * DMODEL;
constexpr size_t OF_WVT  = OF_WKT  + (size_t)DMODEL * DMODEL;
constexpr size_t OF_WOT  = OF_WVT  + (size_t)DMODEL * DMODEL;
constexpr size_t OF_QB   = OF_WOT  + (size_t)DMODEL * DMODEL;
constexpr size_t OF_KPR  = OF_QB   + (size_t)NT * DMODEL;
constexpr size_t OF_KMEM = OF_KPR  + (size_t)NT * DMODEL;
constexpr size_t OF_VTG  = OF_KMEM + (size_t)MSLOT * DMODEL;
constexpr size_t OF_AOUT = OF_VTG  + (size_t)DMODEL * VT_LD;

DEVINL unsigned short f2bf(float f) {
  union { float f; unsigned u; } v; v.f = f;
  unsigned r = v.u + 0x7FFF + ((v.u >> 16) & 1);   // RNE
  return (unsigned short)(r >> 16);
}

#if __has_builtin(__builtin_amdgcn_cvt_pk_bf16_f32)
DEVINL unsigned pack2(float a, float b) {
  auto t = __builtin_amdgcn_cvt_pk_bf16_f32(a, b);
  unsigned r; __builtin_memcpy(&r, &t, 4); return r;
}
#else
DEVINL unsigned pack2(float a, float b) {
  return (unsigned)f2bf(a) | ((unsigned)f2bf(b) << 16);
}
#endif

#if __has_builtin(__builtin_amdgcn_exp2f)
DEVINL float fast_exp2(float x) { return __builtin_amdgcn_exp2f(x); }
#else
DEVINL float fast_exp2(float x) { return exp2f(x); }
#endif

DEVINL f32x4 mfma16(bf16x8 a, bf16x8 b, f32x4 c) {
  return __builtin_amdgcn_mfma_f32_16x16x32_bf16(a, b, c, 0, 0, 0);
}

// async global -> LDS, 16 bytes per lane (global_load_lds_dwordx4)
DEVINL void gload16(const unsigned short* gp, unsigned short* lp) {
  __builtin_amdgcn_global_load_lds(
      (const __attribute__((address_space(1))) unsigned int*)(const void*)gp,
      (__attribute__((address_space(3))) unsigned int*)(void*)lp, 16, 0, 0);
}

// ---------------- conversion kernels ----------------

// Q/K/V fp32 -> bf16, merged: blockIdx.y selects tensor
__global__ __launch_bounds__(256) void cvt3_bf16(const float* __restrict__ q,
                                                 const float* __restrict__ k,
                                                 const float* __restrict__ v,
                                                 unsigned short* __restrict__ dq,
                                                 unsigned short* __restrict__ dk,
                                                 unsigned short* __restrict__ dv) {
  const float* src = (blockIdx.y == 0) ? q : (blockIdx.y == 1) ? k : v;
  unsigned short* dst = (blockIdx.y == 0) ? dq : (blockIdx.y == 1) ? dk : dv;
  int i = (blockIdx.x * 256 + threadIdx.x) * 8;
  float4 v0 = *(const float4*)(src + i);
  float4 v1 = *(const float4*)(src + i + 4);
  union { unsigned u2[4]; uint4 v; } o;
  o.u2[0] = pack2(v0.x, v0.y); o.u2[1] = pack2(v0.z, v0.w);
  o.u2[2] = pack2(v1.x, v1.y); o.u2[3] = pack2(v1.z, v1.w);
  *(uint4*)(dst + i) = o.v;
}

// W [K=1024][N=1024] fp32 -> Wt [N][K] bf16, vectorized 16B stores.
__global__ __launch_bounds__(256) void transpose_cvt4(
    const float* __restrict__ s0, const float* __restrict__ s1,
    const float* __restrict__ s2, const float* __restrict__ s3,
    unsigned short* __restrict__ d0, unsigned short* __restrict__ d1,
    unsigned short* __restrict__ d2, unsigned short* __restrict__ d3) {
  const float* src = (blockIdx.z == 0) ? s0 : (blockIdx.z == 1) ? s1 : (blockIdx.z == 2) ? s2 : s3;
  unsigned short* dst = (blockIdx.z == 0) ? d0 : (blockIdx.z == 1) ? d1 : (blockIdx.z == 2) ? d2 : d3;
  __shared__ float t[32][65];
  const int tid = threadIdx.x;
  const int n0 = blockIdx.x * 32, k0 = blockIdx.y * 64;
  {
    int c = tid & 31, rg = tid >> 5;
#pragma unroll
    for (int rr = 0; rr < 8; ++rr)
      t[c][rg * 8 + rr] = src[(size_t)(k0 + rg * 8 + rr) * DMODEL + n0 + c];
  }
  __syncthreads();
  {
    int n = tid >> 3, ck = tid & 7;
    union { unsigned short u[8]; uint4 v; } o;
#pragma unroll
    for (int j = 0; j < 8; ++j) o.u[j] = f2bf(t[n][ck * 8 + j]);
    *(uint4*)(dst + (size_t)(n0 + n) * DMODEL + k0 + ck * 8) = o.v;
  }
}

// Kmem[j][c] = bf16(mk[j][c] * sqrt(M))
__global__ __launch_bounds__(256) void kmem_cvt(const float* __restrict__ mk,
                                                unsigned short* __restrict__ dst) {
  int i = blockIdx.x * 256 + threadIdx.x;
  dst[i] = f2bf(mk[i] * SCALE_M);
}

// mv [128][1024] -> VtG[c][b*1152 + 1024 + j] = bf16(mv[j][c]*sqrt(M))
__global__ __launch_bounds__(256) void vmem_transpose(const float* __restrict__ mv,
                                                      unsigned short* __restrict__ VtG) {
  __shared__ float t[32][33];
  const int tx = threadIdx.x, ty = threadIdx.y;
  const int j0 = blockIdx.x * 32, c0 = blockIdx.y * 32;
#pragma unroll
  for (int r = 0; r < 4; ++r)
    t[ty + r * 8][tx] = mv[(size_t)(j0 + ty + r * 8) * DMODEL + c0 + tx];
  __syncthreads();
#pragma unroll
  for (int r = 0; r < 4; ++r) {
    int c = c0 + ty + r * 8;
    unsigned short v = f2bf(t[tx][ty + r * 8] * SCALE_M);
#pragma unroll
    for (int bb = 0; bb < BZ; ++bb)
      VtG[(size_t)c * VT_LD + bb * SKM + SEQ + j0 + tx] = v;
  }
}

// ---------------- 128x128 GEMM core (m97 structure: BK=32, 4 waves 2x2,
// wave tile 64x64 = 4x4 accs, LDS rows stride 32 ushorts) ----------------

DEVINL void g128_stage(const unsigned short* rA, const unsigned short* cB,
                       unsigned short* As, unsigned short* Bs, int k0, int tid) {
#pragma unroll
  for (int gi = 0; gi < 2; ++gi) {
    int g = gi * 256 + tid;
    int row = g >> 2, slot = g & 3;
    gload16(rA + (size_t)row * DMODEL + k0 + slot * 8, As + g * 8);
    gload16(cB + (size_t)row * DMODEL + k0 + slot * 8, Bs + g * 8);
  }
}

DEVINL void g128_compute(const unsigned short* As, const unsigned short* Bs,
                         int wr, int wc, int quad, int l16, f32x4 acc[4][4]) {
  bf16x8 af[4], bfr[4];
#pragma unroll
  for (int rb = 0; rb < 4; ++rb)
    af[rb] = *(const bf16x8*)(As + (wr * 64 + rb * 16 + l16) * 32 + quad * 8);
#pragma unroll
  for (int cb = 0; cb < 4; ++cb)
    bfr[cb] = *(const bf16x8*)(Bs + (wc * 64 + cb * 16 + l16) * 32 + quad * 8);
#pragma unroll
  for (int rb = 0; rb < 4; ++rb)
#pragma unroll
    for (int cb = 0; cb < 4; ++cb)
      acc[rb][cb] = mfma16(af[rb], bfr[cb], acc[rb][cb]);
}

// merged Q/K/V projections: 768 blocks; pid = bid>>8 (0:Q 1:K 2:V^T), idx = bid&255.
// idx&7 = n-tile (weight slice pinned per XCD), idx>>3 = m-tile.
__global__ __launch_bounds__(256) void proj_qkv(
    const unsigned short* __restrict__ Qin, const unsigned short* __restrict__ Kin,
    const unsigned short* __restrict__ Vin, const unsigned short* __restrict__ Wqt,
    const unsigned short* __restrict__ Wkt, const unsigned short* __restrict__ Wvt,
    const float* __restrict__ bq, const float* __restrict__ bk,
    const float* __restrict__ bv, unsigned short* __restrict__ Qbp,
    unsigned short* __restrict__ Kprp, unsigned short* __restrict__ VtG) {
  __shared__ unsigned short As[128 * 32];
  __shared__ unsigned short Bs[128 * 32];
  const int tid = threadIdx.x;
  const int pid = blockIdx.x >> 8;
  const int idx = blockIdx.x & 255;
  const int w = tid >> 6, lane = tid & 63, quad = lane >> 4, l16 = lane & 15;
  const int wr = w >> 1, wc = w & 1;

  const unsigned short *rA, *cB;
  int m0, n0;
  if (pid == 0) {
    m0 = (idx >> 3) * 128; n0 = (idx & 7) * 128;
    rA = Qin + (size_t)m0 * DMODEL; cB = Wqt + (size_t)n0 * DMODEL;
  } else if (pid == 1) {
    m0 = (idx >> 3) * 128; n0 = (idx & 7) * 128;
    rA = Kin + (size_t)m0 * DMODEL; cB = Wkt + (size_t)n0 * DMODEL;
  } else {
    m0 = (idx & 7) * 128;            // rows = Wv output dim n
    n0 = (idx >> 3) * 128;           // cols = tokens
    rA = Wvt + (size_t)m0 * DMODEL; cB = Vin + (size_t)n0 * DMODEL;
  }

  f32x4 acc[4][4] = {};
  for (int kt = 0; kt < 32; ++kt) {
    g128_stage(rA, cB, As, Bs, kt * 32, tid);
    __syncthreads();
    g128_compute(As, Bs, wr, wc, quad, l16, acc);
    __syncthreads();
  }

  if (pid < 2) {
    const float* bias = pid ? bk : bq;
    unsigned short* out = pid ? Kprp : Qbp;
#pragma unroll
    for (int rb = 0; rb < 4; ++rb)
#pragma unroll
      for (int cb = 0; cb < 4; ++cb)
#pragma unroll
        for (int r = 0; r < 4; ++r) {
          int row = m0 + wr * 64 + rb * 16 + quad * 4 + r;
          int col = n0 + wc * 64 + cb * 16 + l16;
          out[(size_t)row * DMODEL + col] = f2bf(acc[rb][cb][r] + bias[col]);
        }
  } else {
#pragma unroll
    for (int rb = 0; rb < 4; ++rb)
#pragma unroll
      for (int cb = 0; cb < 4; ++cb)
#pragma unroll
        for (int r = 0; r < 4; ++r) {
          int n = m0 + wr * 64 + rb * 16 + quad * 4 + r;
          int tok = n0 + wc * 64 + cb * 16 + l16;
          int col = tok + (tok >> 10) * MSLOT;   // batch-concat column remap
          VtG[(size_t)n * VT_LD + col] = f2bf(acc[rb][cb][r] + bv[n]);
        }
  }
}

// output GEMM: C[4096][1024] fp32 = Aout @ Wot^T + bo, 128x128 tiles
__global__ __launch_bounds__(256) void gemm_out(const unsigned short* __restrict__ A,
                                                const unsigned short* __restrict__ Wt,
                                                const float* __restrict__ bias,
                                                float* __restrict__ Cout) {
  __shared__ unsigned short As[128 * 32];
  __shared__ unsigned short Bs[128 * 32];
  const int tid = threadIdx.x;
  const int m0 = blockIdx.y * 128, n0 = blockIdx.x * 128;
  const int w = tid >> 6, lane = tid & 63, quad = lane >> 4, l16 = lane & 15;
  const int wr = w >> 1, wc = w & 1;
  const unsigned short* rA = A + (size_t)m0 * DMODEL;
  const unsigned short* cB = Wt + (size_t)n0 * DMODEL;
  f32x4 acc[4][4] = {};
  for (int kt = 0; kt < 32; ++kt) {
    g128_stage(rA, cB, As, Bs, kt * 32, tid);
    __syncthreads();
    g128_compute(As, Bs, wr, wc, quad, l16, acc);
    __syncthreads();
  }
#pragma unroll
  for (int rb = 0; rb < 4; ++rb)
#pragma unroll
    for (int cb = 0; cb < 4; ++cb)
#pragma unroll
      for (int r = 0; r < 4; ++r) {
        int row = m0 + wr * 64 + rb * 16 + quad * 4 + r;
        int col = n0 + wc * 64 + cb * 16 + l16;
        Cout[(size_t)row * DMODEL + col] = acc[rb][cb][r] + bias[col];
      }
}

// ---------------- flash attention: 128 queries/block, fixed-max softmax, S^T ----
// 512 blocks; bid&63 = (b,h) so the 8 q-blocks of one (b,h) share an XCD L2 slice.
// Each wave: 32 queries as two 16-q groups; V-frags shared across groups in PV.
__global__ __launch_bounds__(256) void attn_kernel(const unsigned short* __restrict__ Qb,
                                                   const unsigned short* __restrict__ Kproj,
                                                   const unsigned short* __restrict__ Kmem,
                                                   const unsigned short* __restrict__ VtG,
                                                   unsigned short* __restrict__ Aout) {
  __shared__ unsigned short Ks[64 * 72];        // [key][kd], stride 72
  __shared__ unsigned short Vs[64 * 72];        // [dv][key] (V^T tile)
  __shared__ unsigned short Pl[4 * 32 * 72];    // per-wave P[q(32)][key]
  const int tid = threadIdx.x;
  const int bh = blockIdx.x & 63, qb = blockIdx.x >> 6;
  const int b = bh & 3, h = bh >> 2;
  const int w = tid >> 6, lane = tid & 63, quad = lane >> 4, l16 = lane & 15;
  const int token0 = b * SEQ + qb * 128 + w * 32;
  unsigned short* Pw = Pl + w * 32 * 72;

  const int row0 = tid >> 3, slot0 = tid & 7;
  const int g1 = tid + 256;
  const int row1 = g1 >> 3, slot1 = g1 & 7;

  auto kbase = [&](int tile) -> const unsigned short* {
    return (tile < 16) ? Kproj + (size_t)(b * SEQ + tile * 64) * DMODEL + h * HD
                       : Kmem + (size_t)((tile - 16) * 64) * DMODEL + h * HD;
  };
  auto vbase = [&](int tile) -> const unsigned short* {
    int c0 = (tile < 16) ? b * SKM + tile * 64 : b * SKM + SEQ + (tile - 16) * 64;
    return VtG + (size_t)(h * HD) * VT_LD + c0;
  };

  bf16x8 qf[2][2];   // [qgroup][khalf], B-operand: Q[n=l16][k=quad*8+j(+32t)]
#pragma unroll
  for (int g = 0; g < 2; ++g)
#pragma unroll
    for (int t = 0; t < 2; ++t)
      qf[g][t] = *(const bf16x8*)(Qb + (size_t)(token0 + g * 16 + l16) * DMODEL +
                                  h * HD + t * 32 + quad * 8);

  f32x4 O[2][4] = {};
  float lsum[2] = {0.0f, 0.0f};

  uint4 kr0, kr1, vr0, vr1;
  {
    const unsigned short* kp = kbase(0);
    const unsigned short* vp = vbase(0);
    kr0 = *(const uint4*)(kp + (size_t)row0 * DMODEL + slot0 * 8);
    kr1 = *(const uint4*)(kp + (size_t)row1 * DMODEL + slot1 * 8);
    vr0 = *(const uint4*)(vp + (size_t)row0 * VT_LD + slot0 * 8);
    vr1 = *(const uint4*)(vp + (size_t)row1 * VT_LD + slot1 * 8);
  }

  for (int tile = 0; tile < 18; ++tile) {
    *(uint4*)(Ks + row0 * 72 + slot0 * 8) = kr0;
    *(uint4*)(Ks + row1 * 72 + slot1 * 8) = kr1;
    *(uint4*)(Vs + row0 * 72 + slot0 * 8) = vr0;
    *(uint4*)(Vs + row1 * 72 + slot1 * 8) = vr1;
    __syncthreads();
    if (tile < 17) {   // issue next tile's loads; latency hidden by compute below
      const unsigned short* kp = kbase(tile + 1);
      const unsigned short* vp = vbase(tile + 1);
      kr0 = *(const uint4*)(kp + (size_t)row0 * DMODEL + slot0 * 8);
      kr1 = *(const uint4*)(kp + (size_t)row1 * DMODEL + slot1 * 8);
      vr0 = *(const uint4*)(vp + (size_t)row0 * VT_LD + slot0 * 8);
      vr1 = *(const uint4*)(vp + (size_t)row1 * VT_LD + slot1 * 8);
    }

    // S^T per q-group: A = K rows, B = Q rows. keys = c*16+quad*4+r, q = l16.
#pragma unroll
    for (int g = 0; g < 2; ++g) {
      f32x4 sc[4] = {};
#pragma unroll
      for (int c = 0; c < 4; ++c)
#pragma unroll
        for (int t = 0; t < 2; ++t) {
          bf16x8 kb = *(const bf16x8*)(Ks + (c * 16 + l16) * 72 + t * 32 + quad * 8);
          sc[c] = mfma16(kb, qf[g][t], sc[c]);
        }
#pragma unroll
      for (int c = 0; c < 4; ++c) {
        float p0 = fast_exp2(sc[c][0] * SCEXP);
        float p1 = fast_exp2(sc[c][1] * SCEXP);
        float p2 = fast_exp2(sc[c][2] * SCEXP);
        float p3 = fast_exp2(sc[c][3] * SCEXP);
        lsum[g] += (p0 + p1) + (p2 + p3);
        union { unsigned u[2]; } pk;
        pk.u[0] = pack2(p0, p1);
        pk.u[1] = pack2(p2, p3);
        *(uint2*)(Pw + (g * 16 + l16) * 72 + c * 16 + quad * 4) = *(uint2*)pk.u;
      }
    }
    __builtin_amdgcn_wave_barrier();   // order DS write -> DS read (wave-local)

#pragma unroll
    for (int t2 = 0; t2 < 2; ++t2) {
      bf16x8 pa0 = *(const bf16x8*)(Pw + (0 + l16) * 72 + t2 * 32 + quad * 8);
      bf16x8 pa1 = *(const bf16x8*)(Pw + (16 + l16) * 72 + t2 * 32 + quad * 8);
#pragma unroll
      for (int c2 = 0; c2 < 4; ++c2) {
        bf16x8 vb = *(const bf16x8*)(Vs + (c2 * 16 + l16) * 72 + t2 * 32 + quad * 8);
        O[0][c2] = mfma16(pa0, vb, O[0][c2]);
        O[1][c2] = mfma16(pa1, vb, O[1][c2]);
      }
    }
    __syncthreads();
  }

#pragma unroll
  for (int g = 0; g < 2; ++g) {
    float ls = lsum[g];
    ls += __shfl_xor(ls, 16);
    ls += __shfl_xor(ls, 32);
#pragma unroll
    for (int r = 0; r < 4; ++r) {
      float lv = __shfl(ls, quad * 4 + r, 16);
      float inv = 1.0f / lv;
#pragma unroll
      for (int c2 = 0; c2 < 4; ++c2)
        Aout[(size_t)(token0 + g * 16 + quad * 4 + r) * DMODEL + h * HD + c2 * 16 + l16] =
            f2bf(O[g][c2][r] * inv);
    }
  }
}

// ---------------- launch ----------------
extern "C" void kernel_launch(void* const* d_in, const int* in_sizes, int n_in,
                              void* d_out, int out_size, void* d_ws, size_t ws_size,
                              hipStream_t stream) {
  const float* queries = (const float*)d_in[0];
  const float* keys    = (const float*)d_in[1];
  const float* values  = (const float*)d_in[2];
  const float* Wq = (const float*)d_in[3];
  const float* bq = (const float*)d_in[4];
  const float* Wk = (const float*)d_in[5];
  const float* bk = (const float*)d_in[6];
  const float* Wv = (const float*)d_in[7];
  const float* bv = (const float*)d_in[8];
  const float* Wo = (const float*)d_in[9];
  const float* bo = (const float*)d_in[10];
  const float* mk = (const float*)d_in[11];
  const float* mv = (const float*)d_in[12];

  unsigned short* ws = (unsigned short*)d_ws;
  unsigned short* Qin  = ws + OF_QIN;
  unsigned short* Kin  = ws + OF_KIN;
  unsigned short* Vin  = ws + OF_VIN;
  unsigned short* Wqt  = ws + OF_WQT;
  unsigned short* Wkt  = ws + OF_WKT;
  unsigned short* Wvt  = ws + OF_WVT;
  unsigned short* Wot  = ws + OF_WOT;
  unsigned short* Qbp  = ws + OF_QB;
  unsigned short* Kprp = ws + OF_KPR;
  unsigned short* Kmm  = ws + OF_KMEM;
  unsigned short* VtGp = ws + OF_VTG;
  unsigned short* Aoutp = ws + OF_AOUT;

  cvt3_bf16<<<dim3(2048, 3), 256, 0, stream>>>(queries, keys, values, Qin, Kin, Vin);

  transpose_cvt4<<<dim3(32, 16, 4), 256, 0, stream>>>(Wq, Wk, Wv, Wo, Wqt, Wkt, Wvt, Wot);

  kmem_cvt<<<(MSLOT * DMODEL) / 256, 256, 0, stream>>>(mk, Kmm);
  vmem_transpose<<<dim3(MSLOT / 32, DMODEL / 32), dim3(32, 8), 0, stream>>>(mv, VtGp);

  proj_qkv<<<768, 256, 0, stream>>>(Qin, Kin, Vin, Wqt, Wkt, Wvt, bq, bk, bv,
                                    Qbp, Kprp, VtGp);

  attn_kernel<<<512, 256, 0, stream>>>(Qbp, Kprp, Kmm, VtGp, Aoutp);

  gemm_out<<<dim3(8, 32), 256, 0, stream>>>(Aoutp, Wot, bo, (float*)d_out);
}

// Round 5
// 231.947 us; speedup vs baseline: 1.0594x; 1.0594x over previous
//
#include <hip/hip_runtime.h>

typedef __attribute__((ext_vector_type(8))) __bf16 bf16x8;
typedef __attribute__((ext_vector_type(4))) float f32x4;

#define DEVINL __device__ __forceinline__

constexpr int BZ = 4;
constexpr int SEQ = 1024;
constexpr int DMODEL = 1024;
constexpr int NH = 16;
constexpr int HD = 64;               // dk = dv = 64
constexpr int MSLOT = 128;
constexpr int NT = BZ * SEQ;         // 4096 tokens
constexpr int SKM = SEQ + MSLOT;     // 1152 keys per batch
constexpr int VT_LD = BZ * SKM;      // 4608: leading dim of global V^T
constexpr float SCALE_M = 11.313708498984761f;   // sqrt(128)
constexpr float SCEXP = 0.18033688011112042f;    // (1/sqrt(dk)) * log2(e)
// workspace offsets in bf16 (ushort) elements
constexpr size_t OF_QIN  = 0;
constexpr size_t OF_KIN  = OF_QIN  + (size_t)NT * DMODEL;
constexpr size_t OF_VIN  = OF_KIN  + (size_t)NT * DMODEL;
constexpr size_t OF_WQT  = OF_VIN  + (size_t)NT * DMODEL;
constexpr size_t OF_WKT  = OF_WQT  + (size_t)DMODEL * DMODEL;
constexpr size_t OF_WVT  = OF_WKT  + (size_t)DMODEL * DMODEL;
constexpr size_t OF_WOT  = OF_WVT  + (size_t)DMODEL * DMODEL;
constexpr size_t OF_QB   = OF_WOT  + (size_t)DMODEL * DMODEL;
constexpr size_t OF_KPR  = OF_QB   + (size_t)NT * DMODEL;
constexpr size_t OF_KMEM = OF_KPR  + (size_t)NT * DMODEL;
constexpr size_t OF_VTG  = OF_KMEM + (size_t)MSLOT * DMODEL;
constexpr size_t OF_AOUT = OF_VTG  + (size_t)DMODEL * VT_LD;

DEVINL unsigned short f2bf(float f) {
  union { float f; unsigned u; } v; v.f = f;
  unsigned r = v.u + 0x7FFF + ((v.u >> 16) & 1);   // RNE
  return (unsigned short)(r >> 16);
}

#if __has_builtin(__builtin_amdgcn_cvt_pk_bf16_f32)
DEVINL unsigned pack2(float a, float b) {
  auto t = __builtin_amdgcn_cvt_pk_bf16_f32(a, b);
  unsigned r; __builtin_memcpy(&r, &t, 4); return r;
}
#else
DEVINL unsigned pack2(float a, float b) {
  return (unsigned)f2bf(a) | ((unsigned)f2bf(b) << 16);
}
#endif

#if __has_builtin(__builtin_amdgcn_exp2f)
DEVINL float fast_exp2(float x) { return __builtin_amdgcn_exp2f(x); }
#else
DEVINL float fast_exp2(float x) { return exp2f(x); }
#endif

DEVINL f32x4 mfma16(bf16x8 a, bf16x8 b, f32x4 c) {
  return __builtin_amdgcn_mfma_f32_16x16x32_bf16(a, b, c, 0, 0, 0);
}

// async global -> LDS, 16 bytes per lane (global_load_lds_dwordx4)
DEVINL void gload16(const unsigned short* gp, unsigned short* lp) {
  __builtin_amdgcn_global_load_lds(
      (const __attribute__((address_space(1))) unsigned int*)(const void*)gp,
      (__attribute__((address_space(3))) unsigned int*)(void*)lp, 16, 0, 0);
}

// ---------------- conversion kernels ----------------

// Q/K/V fp32 -> bf16, merged: blockIdx.y selects tensor
__global__ __launch_bounds__(256) void cvt3_bf16(const float* __restrict__ q,
                                                 const float* __restrict__ k,
                                                 const float* __restrict__ v,
                                                 unsigned short* __restrict__ dq,
                                                 unsigned short* __restrict__ dk,
                                                 unsigned short* __restrict__ dv) {
  const float* src = (blockIdx.y == 0) ? q : (blockIdx.y == 1) ? k : v;
  unsigned short* dst = (blockIdx.y == 0) ? dq : (blockIdx.y == 1) ? dk : dv;
  int i = (blockIdx.x * 256 + threadIdx.x) * 8;
  float4 v0 = *(const float4*)(src + i);
  float4 v1 = *(const float4*)(src + i + 4);
  union { unsigned u2[4]; uint4 v; } o;
  o.u2[0] = pack2(v0.x, v0.y); o.u2[1] = pack2(v0.z, v0.w);
  o.u2[2] = pack2(v1.x, v1.y); o.u2[3] = pack2(v1.z, v1.w);
  *(uint4*)(dst + i) = o.v;
}

// W [K=1024][N=1024] fp32 -> Wt [N][K] bf16, vectorized 16B stores.
__global__ __launch_bounds__(256) void transpose_cvt4(
    const float* __restrict__ s0, const float* __restrict__ s1,
    const float* __restrict__ s2, const float* __restrict__ s3,
    unsigned short* __restrict__ d0, unsigned short* __restrict__ d1,
    unsigned short* __restrict__ d2, unsigned short* __restrict__ d3) {
  const float* src = (blockIdx.z == 0) ? s0 : (blockIdx.z == 1) ? s1 : (blockIdx.z == 2) ? s2 : s3;
  unsigned short* dst = (blockIdx.z == 0) ? d0 : (blockIdx.z == 1) ? d1 : (blockIdx.z == 2) ? d2 : d3;
  __shared__ float t[32][65];
  const int tid = threadIdx.x;
  const int n0 = blockIdx.x * 32, k0 = blockIdx.y * 64;
  {
    int c = tid & 31, rg = tid >> 5;
#pragma unroll
    for (int rr = 0; rr < 8; ++rr)
      t[c][rg * 8 + rr] = src[(size_t)(k0 + rg * 8 + rr) * DMODEL + n0 + c];
  }
  __syncthreads();
  {
    int n = tid >> 3, ck = tid & 7;
    union { unsigned short u[8]; uint4 v; } o;
#pragma unroll
    for (int j = 0; j < 8; ++j) o.u[j] = f2bf(t[n][ck * 8 + j]);
    *(uint4*)(dst + (size_t)(n0 + n) * DMODEL + k0 + ck * 8) = o.v;
  }
}

// Kmem[j][c] = bf16(mk[j][c] * sqrt(M))
__global__ __launch_bounds__(256) void kmem_cvt(const float* __restrict__ mk,
                                                unsigned short* __restrict__ dst) {
  int i = blockIdx.x * 256 + threadIdx.x;
  dst[i] = f2bf(mk[i] * SCALE_M);
}

// mv [128][1024] -> VtG[c][b*1152 + 1024 + j] = bf16(mv[j][c]*sqrt(M))
__global__ __launch_bounds__(256) void vmem_transpose(const float* __restrict__ mv,
                                                      unsigned short* __restrict__ VtG) {
  __shared__ float t[32][33];
  const int tx = threadIdx.x, ty = threadIdx.y;
  const int j0 = blockIdx.x * 32, c0 = blockIdx.y * 32;
#pragma unroll
  for (int r = 0; r < 4; ++r)
    t[ty + r * 8][tx] = mv[(size_t)(j0 + ty + r * 8) * DMODEL + c0 + tx];
  __syncthreads();
#pragma unroll
  for (int r = 0; r < 4; ++r) {
    int c = c0 + ty + r * 8;
    unsigned short v = f2bf(t[tx][ty + r * 8] * SCALE_M);
#pragma unroll
    for (int bb = 0; bb < BZ; ++bb)
      VtG[(size_t)c * VT_LD + bb * SKM + SEQ + j0 + tx] = v;
  }
}

// ---------------- GEMM core (BK=64, split column-half buffers, BM=128 BN=64) ----
// (R3's measured-46.5µs proj structure — do not perturb)

DEVINL void gemm_stage(const unsigned short* big, const unsigned short* sm,
                       unsigned short* B0, unsigned short* B1,
                       unsigned short* S0, unsigned short* S1,
                       int k0, int tid) {
#pragma unroll
  for (int hb = 0; hb < 2; ++hb) {
    unsigned short* bl = hb ? B1 : B0;
#pragma unroll
    for (int gi = 0; gi < 2; ++gi) {
      int g = gi * 256 + tid;
      int row = g >> 2, slot = g & 3;
      gload16(big + (size_t)row * DMODEL + k0 + hb * 32 + slot * 8, bl + g * 8);
    }
    unsigned short* sl = hb ? S1 : S0;
    int row = tid >> 2, slot = tid & 3;
    gload16(sm + (size_t)row * DMODEL + k0 + hb * 32 + slot * 8, sl + tid * 8);
  }
}

DEVINL void gemm_compute(const unsigned short* B0, const unsigned short* B1,
                         const unsigned short* S0, const unsigned short* S1,
                         int wr, int wc, int quad, int l16, f32x4 acc[4][2]) {
#pragma unroll
  for (int hb = 0; hb < 2; ++hb) {
    const unsigned short* bl = hb ? B1 : B0;
    const unsigned short* sl = hb ? S1 : S0;
    bf16x8 af[4], bfr[2];
#pragma unroll
    for (int rb = 0; rb < 4; ++rb)
      af[rb] = *(const bf16x8*)(bl + (wr * 64 + rb * 16 + l16) * 32 + quad * 8);
#pragma unroll
    for (int cb = 0; cb < 2; ++cb)
      bfr[cb] = *(const bf16x8*)(sl + (wc * 32 + cb * 16 + l16) * 32 + quad * 8);
#pragma unroll
    for (int rb = 0; rb < 4; ++rb)
#pragma unroll
      for (int cb = 0; cb < 2; ++cb)
        acc[rb][cb] = mfma16(af[rb], bfr[cb], acc[rb][cb]);
  }
}

// merged Q/K/V projections: blocks [0,512) Q, [512,1024) K, [1024,1536) V^T
__global__ __launch_bounds__(256) void proj_qkv(
    const unsigned short* __restrict__ Qin, const unsigned short* __restrict__ Kin,
    const unsigned short* __restrict__ Vin, const unsigned short* __restrict__ Wqt,
    const unsigned short* __restrict__ Wkt, const unsigned short* __restrict__ Wvt,
    const float* __restrict__ bq, const float* __restrict__ bk,
    const float* __restrict__ bv, unsigned short* __restrict__ Qbp,
    unsigned short* __restrict__ Kprp, unsigned short* __restrict__ VtG) {
  __shared__ unsigned short Big0[128 * 32], Big1[128 * 32];
  __shared__ unsigned short Sm0[64 * 32], Sm1[64 * 32];
  const int tid = threadIdx.x;
  const int pid = blockIdx.x >> 9;
  const int idx = blockIdx.x & 511;
  const int w = tid >> 6, lane = tid & 63, quad = lane >> 4, l16 = lane & 15;
  const int wr = w >> 1, wc = w & 1;
  f32x4 acc[4][2] = {};

  if (pid < 2) {
    const unsigned short* A  = pid ? Kin : Qin;
    const unsigned short* Wt = pid ? Wkt : Wqt;
    const float* bias        = pid ? bk : bq;
    unsigned short* out      = pid ? Kprp : Qbp;
    const int n0 = (idx & 15) * 64, m0 = (idx >> 4) * 128;
    const unsigned short* big = A + (size_t)m0 * DMODEL;
    const unsigned short* sm  = Wt + (size_t)n0 * DMODEL;
    for (int kt = 0; kt < 16; ++kt) {
      gemm_stage(big, sm, Big0, Big1, Sm0, Sm1, kt * 64, tid);
      __syncthreads();
      gemm_compute(Big0, Big1, Sm0, Sm1, wr, wc, quad, l16, acc);
      __syncthreads();
    }
#pragma unroll
    for (int rb = 0; rb < 4; ++rb)
#pragma unroll
      for (int cb = 0; cb < 2; ++cb)
#pragma unroll
        for (int r = 0; r < 4; ++r) {
          int row = m0 + wr * 64 + rb * 16 + quad * 4 + r;
          int col = n0 + wc * 32 + cb * 16 + l16;
          out[(size_t)row * DMODEL + col] = f2bf(acc[rb][cb][r] + bias[col]);
        }
  } else {
    const int t0 = (idx & 63) * 64, n0 = (idx >> 6) * 128;
    const unsigned short* big = Wvt + (size_t)n0 * DMODEL;   // n rows
    const unsigned short* sm  = Vin + (size_t)t0 * DMODEL;   // token rows
    for (int kt = 0; kt < 16; ++kt) {
      gemm_stage(big, sm, Big0, Big1, Sm0, Sm1, kt * 64, tid);
      __syncthreads();
      gemm_compute(Big0, Big1, Sm0, Sm1, wr, wc, quad, l16, acc);
      __syncthreads();
    }
#pragma unroll
    for (int rb = 0; rb < 4; ++rb)
#pragma unroll
      for (int cb = 0; cb < 2; ++cb)
#pragma unroll
        for (int r = 0; r < 4; ++r) {
          int n = n0 + wr * 64 + rb * 16 + quad * 4 + r;
          int tok = t0 + wc * 32 + cb * 16 + l16;
          int col = tok + (tok >> 10) * MSLOT;
          VtG[(size_t)n * VT_LD + col] = f2bf(acc[rb][cb][r] + bv[n]);
        }
  }
}

// output GEMM (R2's measured structure): BK=32, BM=128 BN=64, 512 blocks
__global__ __launch_bounds__(256) void gemm_out(const unsigned short* __restrict__ A,
                                                const unsigned short* __restrict__ Wt,
                                                const float* __restrict__ bias,
                                                float* __restrict__ Cout) {
  __shared__ unsigned short As[128 * 32];
  __shared__ unsigned short Bs[64 * 32];
  const int tid = threadIdx.x;
  const int m0 = blockIdx.y * 128;
  const int n0 = blockIdx.x * 64;
  const int w = tid >> 6, lane = tid & 63, quad = lane >> 4, l16 = lane & 15;
  const int wr = w >> 1, wc = w & 1;
  f32x4 acc[4][2] = {};
  for (int kt = 0; kt < 32; ++kt) {
    const int k0 = kt * 32;
#pragma unroll
    for (int gi = 0; gi < 2; ++gi) {
      int g = gi * 256 + tid;
      int row = g >> 2, slot = g & 3;
      gload16(A + (size_t)(m0 + row) * DMODEL + k0 + slot * 8, As + g * 8);
    }
    {
      int row = tid >> 2, slot = tid & 3;
      gload16(Wt + (size_t)(n0 + row) * DMODEL + k0 + slot * 8, Bs + tid * 8);
    }
    __syncthreads();
    bf16x8 af[4], bfr[2];
#pragma unroll
    for (int rb = 0; rb < 4; ++rb)
      af[rb] = *(const bf16x8*)(As + (wr * 64 + rb * 16 + l16) * 32 + quad * 8);
#pragma unroll
    for (int cb = 0; cb < 2; ++cb)
      bfr[cb] = *(const bf16x8*)(Bs + (wc * 32 + cb * 16 + l16) * 32 + quad * 8);
#pragma unroll
    for (int rb = 0; rb < 4; ++rb)
#pragma unroll
      for (int cb = 0; cb < 2; ++cb)
        acc[rb][cb] = mfma16(af[rb], bfr[cb], acc[rb][cb]);
    __syncthreads();
  }
#pragma unroll
  for (int rb = 0; rb < 4; ++rb)
#pragma unroll
    for (int cb = 0; cb < 2; ++cb)
#pragma unroll
      for (int r = 0; r < 4; ++r) {
        int row = m0 + wr * 64 + rb * 16 + quad * 4 + r;
        int col = n0 + wc * 32 + cb * 16 + l16;
        Cout[(size_t)row * DMODEL + col] = acc[rb][cb][r] + bias[col];
      }
}

// ---------------- flash attention: 128 queries/block, fixed-max softmax, S^T ----
// NATURAL grid dim3(8,16,4) = qb-inner (R2's measured-good ordering).
// Each wave: 32 queries as two 16-q groups; V-frags shared across groups in PV.
// Register prefetch of tile t+1 overlaps global latency with tile-t compute.
__global__ __launch_bounds__(256) void attn_kernel(const unsigned short* __restrict__ Qb,
                                                   const unsigned short* __restrict__ Kproj,
                                                   const unsigned short* __restrict__ Kmem,
                                                   const unsigned short* __restrict__ VtG,
                                                   unsigned short* __restrict__ Aout) {
  __shared__ unsigned short Ks[64 * 72];        // [key][kd], stride 72
  __shared__ unsigned short Vs[64 * 72];        // [dv][key] (V^T tile)
  __shared__ unsigned short Pl[4 * 32 * 72];    // per-wave P[q(32)][key]
  const int tid = threadIdx.x;
  const int qb = blockIdx.x, h = blockIdx.y, b = blockIdx.z;
  const int w = tid >> 6, lane = tid & 63, quad = lane >> 4, l16 = lane & 15;
  const int token0 = b * SEQ + qb * 128 + w * 32;
  unsigned short* Pw = Pl + w * 32 * 72;

  const int row0 = tid >> 3, slot0 = tid & 7;
  const int g1 = tid + 256;
  const int row1 = g1 >> 3, slot1 = g1 & 7;

  auto kbase = [&](int tile) -> const unsigned short* {
    return (tile < 16) ? Kproj + (size_t)(b * SEQ + tile * 64) * DMODEL + h * HD
                       : Kmem + (size_t)((tile - 16) * 64) * DMODEL + h * HD;
  };
  auto vbase = [&](int tile) -> const unsigned short* {
    int c0 = (tile < 16) ? b * SKM + tile * 64 : b * SKM + SEQ + (tile - 16) * 64;
    return VtG + (size_t)(h * HD) * VT_LD + c0;
  };

  bf16x8 qf[2][2];   // [qgroup][khalf], B-operand: Q[n=l16][k=quad*8+j(+32t)]
#pragma unroll
  for (int g = 0; g < 2; ++g)
#pragma unroll
    for (int t = 0; t < 2; ++t)
      qf[g][t] = *(const bf16x8*)(Qb + (size_t)(token0 + g * 16 + l16) * DMODEL +
                                  h * HD + t * 32 + quad * 8);

  f32x4 O[2][4] = {};
  float lsum[2] = {0.0f, 0.0f};

  uint4 kr0, kr1, vr0, vr1;
  {
    const unsigned short* kp = kbase(0);
    const unsigned short* vp = vbase(0);
    kr0 = *(const uint4*)(kp + (size_t)row0 * DMODEL + slot0 * 8);
    kr1 = *(const uint4*)(kp + (size_t)row1 * DMODEL + slot1 * 8);
    vr0 = *(const uint4*)(vp + (size_t)row0 * VT_LD + slot0 * 8);
    vr1 = *(const uint4*)(vp + (size_t)row1 * VT_LD + slot1 * 8);
  }

  for (int tile = 0; tile < 18; ++tile) {
    *(uint4*)(Ks + row0 * 72 + slot0 * 8) = kr0;
    *(uint4*)(Ks + row1 * 72 + slot1 * 8) = kr1;
    *(uint4*)(Vs + row0 * 72 + slot0 * 8) = vr0;
    *(uint4*)(Vs + row1 * 72 + slot1 * 8) = vr1;
    __syncthreads();
    if (tile < 17) {   // issue next tile's loads; latency hidden by compute below
      const unsigned short* kp = kbase(tile + 1);
      const unsigned short* vp = vbase(tile + 1);
      kr0 = *(const uint4*)(kp + (size_t)row0 * DMODEL + slot0 * 8);
      kr1 = *(const uint4*)(kp + (size_t)row1 * DMODEL + slot1 * 8);
      vr0 = *(const uint4*)(vp + (size_t)row0 * VT_LD + slot0 * 8);
      vr1 = *(const uint4*)(vp + (size_t)row1 * VT_LD + slot1 * 8);
    }

    // S^T per q-group: A = K rows, B = Q rows. keys = c*16+quad*4+r, q = l16.
#pragma unroll
    for (int g = 0; g < 2; ++g) {
      f32x4 sc[4] = {};
#pragma unroll
      for (int c = 0; c < 4; ++c)
#pragma unroll
        for (int t = 0; t < 2; ++t) {
          bf16x8 kb = *(const bf16x8*)(Ks + (c * 16 + l16) * 72 + t * 32 + quad * 8);
          sc[c] = mfma16(kb, qf[g][t], sc[c]);
        }
#pragma unroll
      for (int c = 0; c < 4; ++c) {
        float p0 = fast_exp2(sc[c][0] * SCEXP);
        float p1 = fast_exp2(sc[c][1] * SCEXP);
        float p2 = fast_exp2(sc[c][2] * SCEXP);
        float p3 = fast_exp2(sc[c][3] * SCEXP);
        lsum[g] += (p0 + p1) + (p2 + p3);
        union { unsigned u[2]; } pk;
        pk.u[0] = pack2(p0, p1);
        pk.u[1] = pack2(p2, p3);
        *(uint2*)(Pw + (g * 16 + l16) * 72 + c * 16 + quad * 4) = *(uint2*)pk.u;
      }
    }
    __builtin_amdgcn_wave_barrier();   // order DS write -> DS read (wave-local)

#pragma unroll
    for (int t2 = 0; t2 < 2; ++t2) {
      bf16x8 pa0 = *(const bf16x8*)(Pw + (0 + l16) * 72 + t2 * 32 + quad * 8);
      bf16x8 pa1 = *(const bf16x8*)(Pw + (16 + l16) * 72 + t2 * 32 + quad * 8);
#pragma unroll
      for (int c2 = 0; c2 < 4; ++c2) {
        bf16x8 vb = *(const bf16x8*)(Vs + (c2 * 16 + l16) * 72 + t2 * 32 + quad * 8);
        O[0][c2] = mfma16(pa0, vb, O[0][c2]);
        O[1][c2] = mfma16(pa1, vb, O[1][c2]);
      }
    }
    __syncthreads();
  }

#pragma unroll
  for (int g = 0; g < 2; ++g) {
    float ls = lsum[g];
    ls += __shfl_xor(ls, 16);
    ls += __shfl_xor(ls, 32);
#pragma unroll
    for (int r = 0; r < 4; ++r) {
      float lv = __shfl(ls, quad * 4 + r, 16);
      float inv = 1.0f / lv;
#pragma unroll
      for (int c2 = 0; c2 < 4; ++c2)
        Aout[(size_t)(token0 + g * 16 + quad * 4 + r) * DMODEL + h * HD + c2 * 16 + l16] =
            f2bf(O[g][c2][r] * inv);
    }
  }
}

// ---------------- launch ----------------
extern "C" void kernel_launch(void* const* d_in, const int* in_sizes, int n_in,
                              void* d_out, int out_size, void* d_ws, size_t ws_size,
                              hipStream_t stream) {
  const float* queries = (const float*)d_in[0];
  const float* keys    = (const float*)d_in[1];
  const float* values  = (const float*)d_in[2];
  const float* Wq = (const float*)d_in[3];
  const float* bq = (const float*)d_in[4];
  const float* Wk = (const float*)d_in[5];
  const float* bk = (const float*)d_in[6];
  const float* Wv = (const float*)d_in[7];
  const float* bv = (const float*)d_in[8];
  const float* Wo = (const float*)d_in[9];
  const float* bo = (const float*)d_in[10];
  const float* mk = (const float*)d_in[11];
  const float* mv = (const float*)d_in[12];

  unsigned short* ws = (unsigned short*)d_ws;
  unsigned short* Qin  = ws + OF_QIN;
  unsigned short* Kin  = ws + OF_KIN;
  unsigned short* Vin  = ws + OF_VIN;
  unsigned short* Wqt  = ws + OF_WQT;
  unsigned short* Wkt  = ws + OF_WKT;
  unsigned short* Wvt  = ws + OF_WVT;
  unsigned short* Wot  = ws + OF_WOT;
  unsigned short* Qbp  = ws + OF_QB;
  unsigned short* Kprp = ws + OF_KPR;
  unsigned short* Kmm  = ws + OF_KMEM;
  unsigned short* VtGp = ws + OF_VTG;
  unsigned short* Aoutp = ws + OF_AOUT;

  cvt3_bf16<<<dim3(2048, 3), 256, 0, stream>>>(queries, keys, values, Qin, Kin, Vin);

  transpose_cvt4<<<dim3(32, 16, 4), 256, 0, stream>>>(Wq, Wk, Wv, Wo, Wqt, Wkt, Wvt, Wot);

  kmem_cvt<<<(MSLOT * DMODEL) / 256, 256, 0, stream>>>(mk, Kmm);
  vmem_transpose<<<dim3(MSLOT / 32, DMODEL / 32), dim3(32, 8), 0, stream>>>(mv, VtGp);

  proj_qkv<<<1536, 256, 0, stream>>>(Qin, Kin, Vin, Wqt, Wkt, Wvt, bq, bk, bv,
                                     Qbp, Kprp, VtGp);

  attn_kernel<<<dim3(8, 16, 4), 256, 0, stream>>>(Qbp, Kprp, Kmm, VtGp, Aoutp);

  gemm_out<<<dim3(16, 32), 256, 0, stream>>>(Aoutp, Wot, bo, (float*)d_out);
}

// Round 6
// 222.248 us; speedup vs baseline: 1.1056x; 1.0436x over previous
//
#include <hip/hip_runtime.h>

typedef __attribute__((ext_vector_type(8))) __bf16 bf16x8;
typedef __attribute__((ext_vector_type(4))) float f32x4;

#define DEVINL __device__ __forceinline__

constexpr int BZ = 4;
constexpr int SEQ = 1024;
constexpr int DMODEL = 1024;
constexpr int NH = 16;
constexpr int HD = 64;               // dk = dv = 64
constexpr int MSLOT = 128;
constexpr int NT = BZ * SEQ;         // 4096 tokens
constexpr int SKM = SEQ + MSLOT;     // 1152 keys per batch
constexpr int VT_LD = BZ * SKM;      // 4608: leading dim of global V^T
constexpr float SCALE_M = 11.313708498984761f;   // sqrt(128)
constexpr float SCEXP = 0.18033688011112042f;    // (1/sqrt(dk)) * log2(e)
// workspace offsets in bf16 (ushort) elements
constexpr size_t OF_QIN  = 0;
constexpr size_t OF_KIN  = OF_QIN  + (size_t)NT * DMODEL;
constexpr size_t OF_VIN  = OF_KIN  + (size_t)NT * DMODEL;
constexpr size_t OF_WQT  = OF_VIN  + (size_t)NT * DMODEL;
constexpr size_t OF_WKT  = OF_WQT  + (size_t)DMODEL * DMODEL;
constexpr size_t OF_WVT  = OF_WKT  + (size_t)DMODEL * DMODEL;
constexpr size_t OF_WOT  = OF_WVT  + (size_t)DMODEL * DMODEL;
constexpr size_t OF_QB   = OF_WOT  + (size_t)DMODEL * DMODEL;
constexpr size_t OF_KPR  = OF_QB   + (size_t)NT * DMODEL;
constexpr size_t OF_KMEM = OF_KPR  + (size_t)NT * DMODEL;
constexpr size_t OF_VTG  = OF_KMEM + (size_t)MSLOT * DMODEL;
constexpr size_t OF_AOUT = OF_VTG  + (size_t)DMODEL * VT_LD;

DEVINL unsigned short f2bf(float f) {
  union { float f; unsigned u; } v; v.f = f;
  unsigned r = v.u + 0x7FFF + ((v.u >> 16) & 1);   // RNE
  return (unsigned short)(r >> 16);
}

#if __has_builtin(__builtin_amdgcn_cvt_pk_bf16_f32)
DEVINL unsigned pack2(float a, float b) {
  auto t = __builtin_amdgcn_cvt_pk_bf16_f32(a, b);
  unsigned r; __builtin_memcpy(&r, &t, 4); return r;
}
#else
DEVINL unsigned pack2(float a, float b) {
  return (unsigned)f2bf(a) | ((unsigned)f2bf(b) << 16);
}
#endif

#if __has_builtin(__builtin_amdgcn_exp2f)
DEVINL float fast_exp2(float x) { return __builtin_amdgcn_exp2f(x); }
#else
DEVINL float fast_exp2(float x) { return exp2f(x); }
#endif

DEVINL f32x4 mfma16(bf16x8 a, bf16x8 b, f32x4 c) {
  return __builtin_amdgcn_mfma_f32_16x16x32_bf16(a, b, c, 0, 0, 0);
}

// async global -> LDS, 16 bytes per lane (global_load_lds_dwordx4)
DEVINL void gload16(const unsigned short* gp, unsigned short* lp) {
  __builtin_amdgcn_global_load_lds(
      (const __attribute__((address_space(1))) unsigned int*)(const void*)gp,
      (__attribute__((address_space(3))) unsigned int*)(void*)lp, 16, 0, 0);
}

// ---------------- merged prep kernel (1 dispatch replaces 4) ----------------
// blocks [0,6144): Q/K/V fp32->bf16      (2048 per tensor)
// blocks [6144,8192): W transpose+cvt    (512 per matrix: 32 n-tiles x 16 k-tiles)
// blocks [8192,8704): Kmem scale+cvt
// blocks [8704,8832): mv -> VtG memory-slot columns (scaled, transposed)
__global__ __launch_bounds__(256) void prep_all(
    const float* __restrict__ q, const float* __restrict__ k, const float* __restrict__ v,
    const float* __restrict__ W0, const float* __restrict__ W1,
    const float* __restrict__ W2, const float* __restrict__ W3,
    const float* __restrict__ mk, const float* __restrict__ mv,
    unsigned short* __restrict__ dq, unsigned short* __restrict__ dk,
    unsigned short* __restrict__ dv,
    unsigned short* __restrict__ d0, unsigned short* __restrict__ d1,
    unsigned short* __restrict__ d2, unsigned short* __restrict__ d3,
    unsigned short* __restrict__ Kmm, unsigned short* __restrict__ VtG) {
  __shared__ float t[32][65];
  const int tid = threadIdx.x;
  const int bid = blockIdx.x;
  if (bid < 6144) {
    const int tz = bid >> 11;
    const float* src = (tz == 0) ? q : (tz == 1) ? k : v;
    unsigned short* dst = (tz == 0) ? dq : (tz == 1) ? dk : dv;
    int i = ((bid & 2047) * 256 + tid) * 8;
    float4 v0 = *(const float4*)(src + i);
    float4 v1 = *(const float4*)(src + i + 4);
    union { unsigned u2[4]; uint4 v; } o;
    o.u2[0] = pack2(v0.x, v0.y); o.u2[1] = pack2(v0.z, v0.w);
    o.u2[2] = pack2(v1.x, v1.y); o.u2[3] = pack2(v1.z, v1.w);
    *(uint4*)(dst + i) = o.v;
  } else if (bid < 8192) {
    const int rel = bid - 6144;
    const int z = rel >> 9, rem = rel & 511;
    const float* src = (z == 0) ? W0 : (z == 1) ? W1 : (z == 2) ? W2 : W3;
    unsigned short* dst = (z == 0) ? d0 : (z == 1) ? d1 : (z == 2) ? d2 : d3;
    const int n0 = (rem & 31) * 32, k0 = (rem >> 5) * 64;
    {
      int c = tid & 31, rg = tid >> 5;
#pragma unroll
      for (int rr = 0; rr < 8; ++rr)
        t[c][rg * 8 + rr] = src[(size_t)(k0 + rg * 8 + rr) * DMODEL + n0 + c];
    }
    __syncthreads();
    {
      int n = tid >> 3, ck = tid & 7;
      union { unsigned short u[8]; uint4 v; } o;
#pragma unroll
      for (int j = 0; j < 8; ++j) o.u[j] = f2bf(t[n][ck * 8 + j]);
      *(uint4*)(dst + (size_t)(n0 + n) * DMODEL + k0 + ck * 8) = o.v;
    }
  } else if (bid < 8704) {
    int i = (bid - 8192) * 256 + tid;
    Kmm[i] = f2bf(mk[i] * SCALE_M);
  } else {
    const int rel = bid - 8704;
    const int j0 = (rel & 3) * 32, c0 = (rel >> 2) * 32;
    const int tx = tid & 31, ty = tid >> 5;
#pragma unroll
    for (int r = 0; r < 4; ++r)
      t[ty + r * 8][tx] = mv[(size_t)(j0 + ty + r * 8) * DMODEL + c0 + tx];
    __syncthreads();
#pragma unroll
    for (int r = 0; r < 4; ++r) {
      int c = c0 + ty + r * 8;
      unsigned short vv = f2bf(t[tx][ty + r * 8] * SCALE_M);
#pragma unroll
      for (int bb = 0; bb < BZ; ++bb)
        VtG[(size_t)c * VT_LD + bb * SKM + SEQ + j0 + tx] = vv;
    }
  }
}

// ---------------- GEMM core (BK=64, split column-half buffers, BM=128 BN=64) ----
// (R3/R5's measured-best GEMM structure — do not perturb)

DEVINL void gemm_stage(const unsigned short* big, const unsigned short* sm,
                       unsigned short* B0, unsigned short* B1,
                       unsigned short* S0, unsigned short* S1,
                       int k0, int tid) {
#pragma unroll
  for (int hb = 0; hb < 2; ++hb) {
    unsigned short* bl = hb ? B1 : B0;
#pragma unroll
    for (int gi = 0; gi < 2; ++gi) {
      int g = gi * 256 + tid;
      int row = g >> 2, slot = g & 3;
      gload16(big + (size_t)row * DMODEL + k0 + hb * 32 + slot * 8, bl + g * 8);
    }
    unsigned short* sl = hb ? S1 : S0;
    int row = tid >> 2, slot = tid & 3;
    gload16(sm + (size_t)row * DMODEL + k0 + hb * 32 + slot * 8, sl + tid * 8);
  }
}

DEVINL void gemm_compute(const unsigned short* B0, const unsigned short* B1,
                         const unsigned short* S0, const unsigned short* S1,
                         int wr, int wc, int quad, int l16, f32x4 acc[4][2]) {
#pragma unroll
  for (int hb = 0; hb < 2; ++hb) {
    const unsigned short* bl = hb ? B1 : B0;
    const unsigned short* sl = hb ? S1 : S0;
    bf16x8 af[4], bfr[2];
#pragma unroll
    for (int rb = 0; rb < 4; ++rb)
      af[rb] = *(const bf16x8*)(bl + (wr * 64 + rb * 16 + l16) * 32 + quad * 8);
#pragma unroll
    for (int cb = 0; cb < 2; ++cb)
      bfr[cb] = *(const bf16x8*)(sl + (wc * 32 + cb * 16 + l16) * 32 + quad * 8);
#pragma unroll
    for (int rb = 0; rb < 4; ++rb)
#pragma unroll
      for (int cb = 0; cb < 2; ++cb)
        acc[rb][cb] = mfma16(af[rb], bfr[cb], acc[rb][cb]);
  }
}

// merged Q/K/V projections: blocks [0,512) Q, [512,1024) K, [1024,1536) V^T
__global__ __launch_bounds__(256) void proj_qkv(
    const unsigned short* __restrict__ Qin, const unsigned short* __restrict__ Kin,
    const unsigned short* __restrict__ Vin, const unsigned short* __restrict__ Wqt,
    const unsigned short* __restrict__ Wkt, const unsigned short* __restrict__ Wvt,
    const float* __restrict__ bq, const float* __restrict__ bk,
    const float* __restrict__ bv, unsigned short* __restrict__ Qbp,
    unsigned short* __restrict__ Kprp, unsigned short* __restrict__ VtG) {
  __shared__ unsigned short Big0[128 * 32], Big1[128 * 32];
  __shared__ unsigned short Sm0[64 * 32], Sm1[64 * 32];
  const int tid = threadIdx.x;
  const int pid = blockIdx.x >> 9;
  const int idx = blockIdx.x & 511;
  const int w = tid >> 6, lane = tid & 63, quad = lane >> 4, l16 = lane & 15;
  const int wr = w >> 1, wc = w & 1;
  f32x4 acc[4][2] = {};

  if (pid < 2) {
    const unsigned short* A  = pid ? Kin : Qin;
    const unsigned short* Wt = pid ? Wkt : Wqt;
    const float* bias        = pid ? bk : bq;
    unsigned short* out      = pid ? Kprp : Qbp;
    const int n0 = (idx & 15) * 64, m0 = (idx >> 4) * 128;
    const unsigned short* big = A + (size_t)m0 * DMODEL;
    const unsigned short* sm  = Wt + (size_t)n0 * DMODEL;
    for (int kt = 0; kt < 16; ++kt) {
      gemm_stage(big, sm, Big0, Big1, Sm0, Sm1, kt * 64, tid);
      __syncthreads();
      gemm_compute(Big0, Big1, Sm0, Sm1, wr, wc, quad, l16, acc);
      __syncthreads();
    }
#pragma unroll
    for (int rb = 0; rb < 4; ++rb)
#pragma unroll
      for (int cb = 0; cb < 2; ++cb)
#pragma unroll
        for (int r = 0; r < 4; ++r) {
          int row = m0 + wr * 64 + rb * 16 + quad * 4 + r;
          int col = n0 + wc * 32 + cb * 16 + l16;
          out[(size_t)row * DMODEL + col] = f2bf(acc[rb][cb][r] + bias[col]);
        }
  } else {
    const int t0 = (idx & 63) * 64, n0 = (idx >> 6) * 128;
    const unsigned short* big = Wvt + (size_t)n0 * DMODEL;   // n rows
    const unsigned short* sm  = Vin + (size_t)t0 * DMODEL;   // token rows
    for (int kt = 0; kt < 16; ++kt) {
      gemm_stage(big, sm, Big0, Big1, Sm0, Sm1, kt * 64, tid);
      __syncthreads();
      gemm_compute(Big0, Big1, Sm0, Sm1, wr, wc, quad, l16, acc);
      __syncthreads();
    }
#pragma unroll
    for (int rb = 0; rb < 4; ++rb)
#pragma unroll
      for (int cb = 0; cb < 2; ++cb)
#pragma unroll
        for (int r = 0; r < 4; ++r) {
          int n = n0 + wr * 64 + rb * 16 + quad * 4 + r;
          int tok = t0 + wc * 32 + cb * 16 + l16;
          int col = tok + (tok >> 10) * MSLOT;
          VtG[(size_t)n * VT_LD + col] = f2bf(acc[rb][cb][r] + bv[n]);
        }
  }
}

// output GEMM, BK=64 split-buffer (same structure as proj): 512 blocks
__global__ __launch_bounds__(256) void gemm_out(const unsigned short* __restrict__ A,
                                                const unsigned short* __restrict__ Wt,
                                                const float* __restrict__ bias,
                                                float* __restrict__ Cout) {
  __shared__ unsigned short Big0[128 * 32], Big1[128 * 32];
  __shared__ unsigned short Sm0[64 * 32], Sm1[64 * 32];
  const int tid = threadIdx.x;
  const int idx = blockIdx.x;
  const int n0 = (idx & 15) * 64, m0 = (idx >> 4) * 128;
  const int w = tid >> 6, lane = tid & 63, quad = lane >> 4, l16 = lane & 15;
  const int wr = w >> 1, wc = w & 1;
  f32x4 acc[4][2] = {};
  const unsigned short* big = A + (size_t)m0 * DMODEL;
  const unsigned short* sm  = Wt + (size_t)n0 * DMODEL;
  for (int kt = 0; kt < 16; ++kt) {
    gemm_stage(big, sm, Big0, Big1, Sm0, Sm1, kt * 64, tid);
    __syncthreads();
    gemm_compute(Big0, Big1, Sm0, Sm1, wr, wc, quad, l16, acc);
    __syncthreads();
  }
#pragma unroll
  for (int rb = 0; rb < 4; ++rb)
#pragma unroll
    for (int cb = 0; cb < 2; ++cb)
#pragma unroll
      for (int r = 0; r < 4; ++r) {
        int row = m0 + wr * 64 + rb * 16 + quad * 4 + r;
        int col = n0 + wc * 32 + cb * 16 + l16;
        Cout[(size_t)row * DMODEL + col] = acc[rb][cb][r] + bias[col];
      }
}

// ---------------- flash attention: 128 queries/block, fixed-max softmax, S^T ----
// XCD swizzle: bid = qb*64 + bh. Under round-robin XCD=bid%8, the q-blocks of
// all (b,h) with bh%8==x land on XCD x -> per-XCD K/V footprint 8*295KB=2.4MB
// fits the 4MB L2 -> K/V fetched ~once per XCD.
// Each wave: 32 queries as two 16-q groups; V-frags shared across groups in PV.
// Register prefetch of tile t+1 overlaps global latency with tile-t compute.
__global__ __launch_bounds__(256) void attn_kernel(const unsigned short* __restrict__ Qb,
                                                   const unsigned short* __restrict__ Kproj,
                                                   const unsigned short* __restrict__ Kmem,
                                                   const unsigned short* __restrict__ VtG,
                                                   unsigned short* __restrict__ Aout) {
  __shared__ unsigned short Ks[64 * 72];        // [key][kd], stride 72
  __shared__ unsigned short Vs[64 * 72];        // [dv][key] (V^T tile)
  __shared__ unsigned short Pl[4 * 32 * 72];    // per-wave P[q(32)][key]
  const int tid = threadIdx.x;
  const int bh = blockIdx.x & 63, qb = blockIdx.x >> 6;
  const int b = bh & 3, h = bh >> 2;
  const int w = tid >> 6, lane = tid & 63, quad = lane >> 4, l16 = lane & 15;
  const int token0 = b * SEQ + qb * 128 + w * 32;
  unsigned short* Pw = Pl + w * 32 * 72;

  const int row0 = tid >> 3, slot0 = tid & 7;
  const int g1 = tid + 256;
  const int row1 = g1 >> 3, slot1 = g1 & 7;

  auto kbase = [&](int tile) -> const unsigned short* {
    return (tile < 16) ? Kproj + (size_t)(b * SEQ + tile * 64) * DMODEL + h * HD
                       : Kmem + (size_t)((tile - 16) * 64) * DMODEL + h * HD;
  };
  auto vbase = [&](int tile) -> const unsigned short* {
    int c0 = (tile < 16) ? b * SKM + tile * 64 : b * SKM + SEQ + (tile - 16) * 64;
    return VtG + (size_t)(h * HD) * VT_LD + c0;
  };

  bf16x8 qf[2][2];   // [qgroup][khalf], B-operand: Q[n=l16][k=quad*8+j(+32t)]
#pragma unroll
  for (int g = 0; g < 2; ++g)
#pragma unroll
    for (int t = 0; t < 2; ++t)
      qf[g][t] = *(const bf16x8*)(Qb + (size_t)(token0 + g * 16 + l16) * DMODEL +
                                  h * HD + t * 32 + quad * 8);

  f32x4 O[2][4] = {};
  float lsum[2] = {0.0f, 0.0f};

  uint4 kr0, kr1, vr0, vr1;
  {
    const unsigned short* kp = kbase(0);
    const unsigned short* vp = vbase(0);
    kr0 = *(const uint4*)(kp + (size_t)row0 * DMODEL + slot0 * 8);
    kr1 = *(const uint4*)(kp + (size_t)row1 * DMODEL + slot1 * 8);
    vr0 = *(const uint4*)(vp + (size_t)row0 * VT_LD + slot0 * 8);
    vr1 = *(const uint4*)(vp + (size_t)row1 * VT_LD + slot1 * 8);
  }

  for (int tile = 0; tile < 18; ++tile) {
    *(uint4*)(Ks + row0 * 72 + slot0 * 8) = kr0;
    *(uint4*)(Ks + row1 * 72 + slot1 * 8) = kr1;
    *(uint4*)(Vs + row0 * 72 + slot0 * 8) = vr0;
    *(uint4*)(Vs + row1 * 72 + slot1 * 8) = vr1;
    __syncthreads();
    if (tile < 17) {   // issue next tile's loads; latency hidden by compute below
      const unsigned short* kp = kbase(tile + 1);
      const unsigned short* vp = vbase(tile + 1);
      kr0 = *(const uint4*)(kp + (size_t)row0 * DMODEL + slot0 * 8);
      kr1 = *(const uint4*)(kp + (size_t)row1 * DMODEL + slot1 * 8);
      vr0 = *(const uint4*)(vp + (size_t)row0 * VT_LD + slot0 * 8);
      vr1 = *(const uint4*)(vp + (size_t)row1 * VT_LD + slot1 * 8);
    }

    // S^T per q-group: A = K rows, B = Q rows. keys = c*16+quad*4+r, q = l16.
#pragma unroll
    for (int g = 0; g < 2; ++g) {
      f32x4 sc[4] = {};
#pragma unroll
      for (int c = 0; c < 4; ++c)
#pragma unroll
        for (int t = 0; t < 2; ++t) {
          bf16x8 kb = *(const bf16x8*)(Ks + (c * 16 + l16) * 72 + t * 32 + quad * 8);
          sc[c] = mfma16(kb, qf[g][t], sc[c]);
        }
#pragma unroll
      for (int c = 0; c < 4; ++c) {
        float p0 = fast_exp2(sc[c][0] * SCEXP);
        float p1 = fast_exp2(sc[c][1] * SCEXP);
        float p2 = fast_exp2(sc[c][2] * SCEXP);
        float p3 = fast_exp2(sc[c][3] * SCEXP);
        lsum[g] += (p0 + p1) + (p2 + p3);
        union { unsigned u[2]; } pk;
        pk.u[0] = pack2(p0, p1);
        pk.u[1] = pack2(p2, p3);
        *(uint2*)(Pw + (g * 16 + l16) * 72 + c * 16 + quad * 4) = *(uint2*)pk.u;
      }
    }
    __builtin_amdgcn_wave_barrier();   // order DS write -> DS read (wave-local)

#pragma unroll
    for (int t2 = 0; t2 < 2; ++t2) {
      bf16x8 pa0 = *(const bf16x8*)(Pw + (0 + l16) * 72 + t2 * 32 + quad * 8);
      bf16x8 pa1 = *(const bf16x8*)(Pw + (16 + l16) * 72 + t2 * 32 + quad * 8);
#pragma unroll
      for (int c2 = 0; c2 < 4; ++c2) {
        bf16x8 vb = *(const bf16x8*)(Vs + (c2 * 16 + l16) * 72 + t2 * 32 + quad * 8);
        O[0][c2] = mfma16(pa0, vb, O[0][c2]);
        O[1][c2] = mfma16(pa1, vb, O[1][c2]);
      }
    }
    __syncthreads();
  }

#pragma unroll
  for (int g = 0; g < 2; ++g) {
    float ls = lsum[g];
    ls += __shfl_xor(ls, 16);
    ls += __shfl_xor(ls, 32);
#pragma unroll
    for (int r = 0; r < 4; ++r) {
      float lv = __shfl(ls, quad * 4 + r, 16);
      float inv = 1.0f / lv;
#pragma unroll
      for (int c2 = 0; c2 < 4; ++c2)
        Aout[(size_t)(token0 + g * 16 + quad * 4 + r) * DMODEL + h * HD + c2 * 16 + l16] =
            f2bf(O[g][c2][r] * inv);
    }
  }
}

// ---------------- launch ----------------
extern "C" void kernel_launch(void* const* d_in, const int* in_sizes, int n_in,
                              void* d_out, int out_size, void* d_ws, size_t ws_size,
                              hipStream_t stream) {
  const float* queries = (const float*)d_in[0];
  const float* keys    = (const float*)d_in[1];
  const float* values  = (const float*)d_in[2];
  const float* Wq = (const float*)d_in[3];
  const float* bq = (const float*)d_in[4];
  const float* Wk = (const float*)d_in[5];
  const float* bk = (const float*)d_in[6];
  const float* Wv = (const float*)d_in[7];
  const float* bv = (const float*)d_in[8];
  const float* Wo = (const float*)d_in[9];
  const float* bo = (const float*)d_in[10];
  const float* mk = (const float*)d_in[11];
  const float* mv = (const float*)d_in[12];

  unsigned short* ws = (unsigned short*)d_ws;
  unsigned short* Qin  = ws + OF_QIN;
  unsigned short* Kin  = ws + OF_KIN;
  unsigned short* Vin  = ws + OF_VIN;
  unsigned short* Wqt  = ws + OF_WQT;
  unsigned short* Wkt  = ws + OF_WKT;
  unsigned short* Wvt  = ws + OF_WVT;
  unsigned short* Wot  = ws + OF_WOT;
  unsigned short* Qbp  = ws + OF_QB;
  unsigned short* Kprp = ws + OF_KPR;
  unsigned short* Kmm  = ws + OF_KMEM;
  unsigned short* VtGp = ws + OF_VTG;
  unsigned short* Aoutp = ws + OF_AOUT;

  prep_all<<<8832, 256, 0, stream>>>(queries, keys, values, Wq, Wk, Wv, Wo, mk, mv,
                                     Qin, Kin, Vin, Wqt, Wkt, Wvt, Wot, Kmm, VtGp);

  proj_qkv<<<1536, 256, 0, stream>>>(Qin, Kin, Vin, Wqt, Wkt, Wvt, bq, bk, bv,
                                     Qbp, Kprp, VtGp);

  attn_kernel<<<512, 256, 0, stream>>>(Qbp, Kprp, Kmm, VtGp, Aoutp);

  gemm_out<<<512, 256, 0, stream>>>(Aoutp, Wot, bo, (float*)d_out);
}

// Round 7
// 217.903 us; speedup vs baseline: 1.1276x; 1.0199x over previous
//
#include <hip/hip_runtime.h>

typedef __attribute__((ext_vector_type(8))) __bf16 bf16x8;
typedef __attribute__((ext_vector_type(4))) float f32x4;

#define DEVINL __device__ __forceinline__

constexpr int BZ = 4;
constexpr int SEQ = 1024;
constexpr int DMODEL = 1024;
constexpr int NH = 16;
constexpr int HD = 64;               // dk = dv = 64
constexpr int MSLOT = 128;
constexpr int NT = BZ * SEQ;         // 4096 tokens
constexpr int SKM = SEQ + MSLOT;     // 1152 keys per batch
constexpr int VT_LD = BZ * SKM;      // 4608: leading dim of global V^T
constexpr float SCALE_M = 11.313708498984761f;   // sqrt(128)
constexpr float SCEXP = 0.18033688011112042f;    // (1/sqrt(dk)) * log2(e)
// workspace offsets in bf16 (ushort) elements
constexpr size_t OF_QIN  = 0;
constexpr size_t OF_KIN  = OF_QIN  + (size_t)NT * DMODEL;
constexpr size_t OF_VIN  = OF_KIN  + (size_t)NT * DMODEL;
constexpr size_t OF_WQT  = OF_VIN  + (size_t)NT * DMODEL;
constexpr size_t OF_WKT  = OF_WQT  + (size_t)DMODEL * DMODEL;
constexpr size_t OF_WVT  = OF_WKT  + (size_t)DMODEL * DMODEL;
constexpr size_t OF_WOT  = OF_WVT  + (size_t)DMODEL * DMODEL;
constexpr size_t OF_QB   = OF_WOT  + (size_t)DMODEL * DMODEL;
constexpr size_t OF_KPR  = OF_QB   + (size_t)NT * DMODEL;
constexpr size_t OF_KMEM = OF_KPR  + (size_t)NT * DMODEL;
constexpr size_t OF_VTG  = OF_KMEM + (size_t)MSLOT * DMODEL;
constexpr size_t OF_AOUT = OF_VTG  + (size_t)DMODEL * VT_LD;

DEVINL unsigned short f2bf(float f) {
  union { float f; unsigned u; } v; v.f = f;
  unsigned r = v.u + 0x7FFF + ((v.u >> 16) & 1);   // RNE
  return (unsigned short)(r >> 16);
}

#if __has_builtin(__builtin_amdgcn_cvt_pk_bf16_f32)
DEVINL unsigned pack2(float a, float b) {
  auto t = __builtin_amdgcn_cvt_pk_bf16_f32(a, b);
  unsigned r; __builtin_memcpy(&r, &t, 4); return r;
}
#else
DEVINL unsigned pack2(float a, float b) {
  return (unsigned)f2bf(a) | ((unsigned)f2bf(b) << 16);
}
#endif

#if __has_builtin(__builtin_amdgcn_exp2f)
DEVINL float fast_exp2(float x) { return __builtin_amdgcn_exp2f(x); }
#else
DEVINL float fast_exp2(float x) { return exp2f(x); }
#endif

DEVINL f32x4 mfma16(bf16x8 a, bf16x8 b, f32x4 c) {
  return __builtin_amdgcn_mfma_f32_16x16x32_bf16(a, b, c, 0, 0, 0);
}

// async global -> LDS, 16 bytes per lane (global_load_lds_dwordx4)
DEVINL void gload16(const unsigned short* gp, unsigned short* lp) {
  __builtin_amdgcn_global_load_lds(
      (const __attribute__((address_space(1))) unsigned int*)(const void*)gp,
      (__attribute__((address_space(3))) unsigned int*)(void*)lp, 16, 0, 0);
}

// ---------------- merged prep kernel ----------------
__global__ __launch_bounds__(256) void prep_all(
    const float* __restrict__ q, const float* __restrict__ k, const float* __restrict__ v,
    const float* __restrict__ W0, const float* __restrict__ W1,
    const float* __restrict__ W2, const float* __restrict__ W3,
    const float* __restrict__ mk, const float* __restrict__ mv,
    unsigned short* __restrict__ dq, unsigned short* __restrict__ dk,
    unsigned short* __restrict__ dv,
    unsigned short* __restrict__ d0, unsigned short* __restrict__ d1,
    unsigned short* __restrict__ d2, unsigned short* __restrict__ d3,
    unsigned short* __restrict__ Kmm, unsigned short* __restrict__ VtG) {
  __shared__ float t[32][65];
  const int tid = threadIdx.x;
  const int bid = blockIdx.x;
  if (bid < 6144) {
    const int tz = bid >> 11;
    const float* src = (tz == 0) ? q : (tz == 1) ? k : v;
    unsigned short* dst = (tz == 0) ? dq : (tz == 1) ? dk : dv;
    int i = ((bid & 2047) * 256 + tid) * 8;
    float4 v0 = *(const float4*)(src + i);
    float4 v1 = *(const float4*)(src + i + 4);
    union { unsigned u2[4]; uint4 v; } o;
    o.u2[0] = pack2(v0.x, v0.y); o.u2[1] = pack2(v0.z, v0.w);
    o.u2[2] = pack2(v1.x, v1.y); o.u2[3] = pack2(v1.z, v1.w);
    *(uint4*)(dst + i) = o.v;
  } else if (bid < 8192) {
    const int rel = bid - 6144;
    const int z = rel >> 9, rem = rel & 511;
    const float* src = (z == 0) ? W0 : (z == 1) ? W1 : (z == 2) ? W2 : W3;
    unsigned short* dst = (z == 0) ? d0 : (z == 1) ? d1 : (z == 2) ? d2 : d3;
    const int n0 = (rem & 31) * 32, k0 = (rem >> 5) * 64;
    {
      int c = tid & 31, rg = tid >> 5;
#pragma unroll
      for (int rr = 0; rr < 8; ++rr)
        t[c][rg * 8 + rr] = src[(size_t)(k0 + rg * 8 + rr) * DMODEL + n0 + c];
    }
    __syncthreads();
    {
      int n = tid >> 3, ck = tid & 7;
      union { unsigned short u[8]; uint4 v; } o;
#pragma unroll
      for (int j = 0; j < 8; ++j) o.u[j] = f2bf(t[n][ck * 8 + j]);
      *(uint4*)(dst + (size_t)(n0 + n) * DMODEL + k0 + ck * 8) = o.v;
    }
  } else if (bid < 8704) {
    int i = (bid - 8192) * 256 + tid;
    Kmm[i] = f2bf(mk[i] * SCALE_M);
  } else {
    const int rel = bid - 8704;
    const int j0 = (rel & 3) * 32, c0 = (rel >> 2) * 32;
    const int tx = tid & 31, ty = tid >> 5;
#pragma unroll
    for (int r = 0; r < 4; ++r)
      t[ty + r * 8][tx] = mv[(size_t)(j0 + ty + r * 8) * DMODEL + c0 + tx];
    __syncthreads();
#pragma unroll
    for (int r = 0; r < 4; ++r) {
      int c = c0 + ty + r * 8;
      unsigned short vv = f2bf(t[tx][ty + r * 8] * SCALE_M);
#pragma unroll
      for (int bb = 0; bb < BZ; ++bb)
        VtG[(size_t)c * VT_LD + bb * SKM + SEQ + j0 + tx] = vv;
    }
  }
}

// ---------------- GEMM core (BK=64, split column-half buffers, BM=128 BN=64) ----

DEVINL void gemm_stage(const unsigned short* big, const unsigned short* sm,
                       unsigned short* B0, unsigned short* B1,
                       unsigned short* S0, unsigned short* S1,
                       int k0, int tid) {
#pragma unroll
  for (int hb = 0; hb < 2; ++hb) {
    unsigned short* bl = hb ? B1 : B0;
#pragma unroll
    for (int gi = 0; gi < 2; ++gi) {
      int g = gi * 256 + tid;
      int row = g >> 2, slot = g & 3;
      gload16(big + (size_t)row * DMODEL + k0 + hb * 32 + slot * 8, bl + g * 8);
    }
    unsigned short* sl = hb ? S1 : S0;
    int row = tid >> 2, slot = tid & 3;
    gload16(sm + (size_t)row * DMODEL + k0 + hb * 32 + slot * 8, sl + tid * 8);
  }
}

DEVINL void gemm_compute(const unsigned short* B0, const unsigned short* B1,
                         const unsigned short* S0, const unsigned short* S1,
                         int wr, int wc, int quad, int l16, f32x4 acc[4][2]) {
#pragma unroll
  for (int hb = 0; hb < 2; ++hb) {
    const unsigned short* bl = hb ? B1 : B0;
    const unsigned short* sl = hb ? S1 : S0;
    bf16x8 af[4], bfr[2];
#pragma unroll
    for (int rb = 0; rb < 4; ++rb)
      af[rb] = *(const bf16x8*)(bl + (wr * 64 + rb * 16 + l16) * 32 + quad * 8);
#pragma unroll
    for (int cb = 0; cb < 2; ++cb)
      bfr[cb] = *(const bf16x8*)(sl + (wc * 32 + cb * 16 + l16) * 32 + quad * 8);
#pragma unroll
    for (int rb = 0; rb < 4; ++rb)
#pragma unroll
      for (int cb = 0; cb < 2; ++cb)
        acc[rb][cb] = mfma16(af[rb], bfr[cb], acc[rb][cb]);
  }
}

// merged Q/K/V projections: blocks [0,512) Q, [512,1024) K, [1024,1536) V^T
// Q/K block remap: m = idx&31, n = idx>>5 so bid%8 = m%8 (activation-co-located:
// each 256KB A-tile stays on one XCD's L2; weight slabs replicated - cheaper side).
// V part already token-co-located (idx%8 = t%8).
__global__ __launch_bounds__(256) void proj_qkv(
    const unsigned short* __restrict__ Qin, const unsigned short* __restrict__ Kin,
    const unsigned short* __restrict__ Vin, const unsigned short* __restrict__ Wqt,
    const unsigned short* __restrict__ Wkt, const unsigned short* __restrict__ Wvt,
    const float* __restrict__ bq, const float* __restrict__ bk,
    const float* __restrict__ bv, unsigned short* __restrict__ Qbp,
    unsigned short* __restrict__ Kprp, unsigned short* __restrict__ VtG) {
  __shared__ unsigned short Big0[128 * 32], Big1[128 * 32];
  __shared__ unsigned short Sm0[64 * 32], Sm1[64 * 32];
  const int tid = threadIdx.x;
  const int pid = blockIdx.x >> 9;
  const int idx = blockIdx.x & 511;
  const int w = tid >> 6, lane = tid & 63, quad = lane >> 4, l16 = lane & 15;
  const int wr = w >> 1, wc = w & 1;
  f32x4 acc[4][2] = {};

  if (pid < 2) {
    const unsigned short* A  = pid ? Kin : Qin;
    const unsigned short* Wt = pid ? Wkt : Wqt;
    const float* bias        = pid ? bk : bq;
    unsigned short* out      = pid ? Kprp : Qbp;
    const int m0 = (idx & 31) * 128, n0 = (idx >> 5) * 64;   // bid%8 = m%8
    const unsigned short* big = A + (size_t)m0 * DMODEL;
    const unsigned short* sm  = Wt + (size_t)n0 * DMODEL;
    for (int kt = 0; kt < 16; ++kt) {
      gemm_stage(big, sm, Big0, Big1, Sm0, Sm1, kt * 64, tid);
      __syncthreads();
      gemm_compute(Big0, Big1, Sm0, Sm1, wr, wc, quad, l16, acc);
      __syncthreads();
    }
#pragma unroll
    for (int rb = 0; rb < 4; ++rb)
#pragma unroll
      for (int cb = 0; cb < 2; ++cb)
#pragma unroll
        for (int r = 0; r < 4; ++r) {
          int row = m0 + wr * 64 + rb * 16 + quad * 4 + r;
          int col = n0 + wc * 32 + cb * 16 + l16;
          out[(size_t)row * DMODEL + col] = f2bf(acc[rb][cb][r] + bias[col]);
        }
  } else {
    const int t0 = (idx & 63) * 64, n0 = (idx >> 6) * 128;
    const unsigned short* big = Wvt + (size_t)n0 * DMODEL;   // n rows
    const unsigned short* sm  = Vin + (size_t)t0 * DMODEL;   // token rows
    for (int kt = 0; kt < 16; ++kt) {
      gemm_stage(big, sm, Big0, Big1, Sm0, Sm1, kt * 64, tid);
      __syncthreads();
      gemm_compute(Big0, Big1, Sm0, Sm1, wr, wc, quad, l16, acc);
      __syncthreads();
    }
#pragma unroll
    for (int rb = 0; rb < 4; ++rb)
#pragma unroll
      for (int cb = 0; cb < 2; ++cb)
#pragma unroll
        for (int r = 0; r < 4; ++r) {
          int n = n0 + wr * 64 + rb * 16 + quad * 4 + r;
          int tok = t0 + wc * 32 + cb * 16 + l16;
          int col = tok + (tok >> 10) * MSLOT;
          VtG[(size_t)n * VT_LD + col] = f2bf(acc[rb][cb][r] + bv[n]);
        }
  }
}

// output GEMM, BK=64 split-buffer, activation-co-located (bid%8 = m%8)
__global__ __launch_bounds__(256) void gemm_out(const unsigned short* __restrict__ A,
                                                const unsigned short* __restrict__ Wt,
                                                const float* __restrict__ bias,
                                                float* __restrict__ Cout) {
  __shared__ unsigned short Big0[128 * 32], Big1[128 * 32];
  __shared__ unsigned short Sm0[64 * 32], Sm1[64 * 32];
  const int tid = threadIdx.x;
  const int idx = blockIdx.x;
  const int m0 = (idx & 31) * 128, n0 = (idx >> 5) * 64;    // bid%8 = m%8
  const int w = tid >> 6, lane = tid & 63, quad = lane >> 4, l16 = lane & 15;
  const int wr = w >> 1, wc = w & 1;
  f32x4 acc[4][2] = {};
  const unsigned short* big = A + (size_t)m0 * DMODEL;
  const unsigned short* sm  = Wt + (size_t)n0 * DMODEL;
  for (int kt = 0; kt < 16; ++kt) {
    gemm_stage(big, sm, Big0, Big1, Sm0, Sm1, kt * 64, tid);
    __syncthreads();
    gemm_compute(Big0, Big1, Sm0, Sm1, wr, wc, quad, l16, acc);
    __syncthreads();
  }
#pragma unroll
  for (int rb = 0; rb < 4; ++rb)
#pragma unroll
    for (int cb = 0; cb < 2; ++cb)
#pragma unroll
      for (int r = 0; r < 4; ++r) {
        int row = m0 + wr * 64 + rb * 16 + quad * 4 + r;
        int col = n0 + wc * 32 + cb * 16 + l16;
        Cout[(size_t)row * DMODEL + col] = acc[rb][cb][r] + bias[col];
      }
}

// ---------------- flash attention: 64 queries/block, fixed-max softmax, S^T ----
// 1024 blocks, swizzle bid = qb*64 + bh (bid%8 = bh%8: K/V co-located per XCD).
// 4 blocks/CU resident (LDS 27KB): exp2-VALU of one block overlaps MFMA of others.
__global__ __launch_bounds__(256) void attn_kernel(const unsigned short* __restrict__ Qb,
                                                   const unsigned short* __restrict__ Kproj,
                                                   const unsigned short* __restrict__ Kmem,
                                                   const unsigned short* __restrict__ VtG,
                                                   unsigned short* __restrict__ Aout) {
  __shared__ unsigned short Ks[64 * 72];        // [key][kd], stride 72
  __shared__ unsigned short Vs[64 * 72];        // [dv][key] (V^T tile)
  __shared__ unsigned short Pl[4 * 16 * 72];    // per-wave P[q][key]
  const int tid = threadIdx.x;
  const int bh = blockIdx.x & 63, qb = blockIdx.x >> 6;
  const int b = bh & 3, h = bh >> 2;
  const int w = tid >> 6, lane = tid & 63, quad = lane >> 4, l16 = lane & 15;
  const int token0 = b * SEQ + qb * 64 + w * 16;
  unsigned short* Pw = Pl + w * 16 * 72;

  const int row0 = tid >> 3, slot0 = tid & 7;
  const int g1 = tid + 256;
  const int row1 = g1 >> 3, slot1 = g1 & 7;

  auto kbase = [&](int tile) -> const unsigned short* {
    return (tile < 16) ? Kproj + (size_t)(b * SEQ + tile * 64) * DMODEL + h * HD
                       : Kmem + (size_t)((tile - 16) * 64) * DMODEL + h * HD;
  };
  auto vbase = [&](int tile) -> const unsigned short* {
    int c0 = (tile < 16) ? b * SKM + tile * 64 : b * SKM + SEQ + (tile - 16) * 64;
    return VtG + (size_t)(h * HD) * VT_LD + c0;
  };

  bf16x8 qf[2];   // B-operand: Q[n=l16][k = quad*8+j (+32t)]
#pragma unroll
  for (int t = 0; t < 2; ++t)
    qf[t] = *(const bf16x8*)(Qb + (size_t)(token0 + l16) * DMODEL + h * HD + t * 32 + quad * 8);

  f32x4 O[4] = {};
  float lsum = 0.0f;

  uint4 kr0, kr1, vr0, vr1;
  {
    const unsigned short* kp = kbase(0);
    const unsigned short* vp = vbase(0);
    kr0 = *(const uint4*)(kp + (size_t)row0 * DMODEL + slot0 * 8);
    kr1 = *(const uint4*)(kp + (size_t)row1 * DMODEL + slot1 * 8);
    vr0 = *(const uint4*)(vp + (size_t)row0 * VT_LD + slot0 * 8);
    vr1 = *(const uint4*)(vp + (size_t)row1 * VT_LD + slot1 * 8);
  }

  for (int tile = 0; tile < 18; ++tile) {
    *(uint4*)(Ks + row0 * 72 + slot0 * 8) = kr0;
    *(uint4*)(Ks + row1 * 72 + slot1 * 8) = kr1;
    *(uint4*)(Vs + row0 * 72 + slot0 * 8) = vr0;
    *(uint4*)(Vs + row1 * 72 + slot1 * 8) = vr1;
    __syncthreads();
    if (tile < 17) {   // prefetch next tile; latency hidden by compute below
      const unsigned short* kp = kbase(tile + 1);
      const unsigned short* vp = vbase(tile + 1);
      kr0 = *(const uint4*)(kp + (size_t)row0 * DMODEL + slot0 * 8);
      kr1 = *(const uint4*)(kp + (size_t)row1 * DMODEL + slot1 * 8);
      vr0 = *(const uint4*)(vp + (size_t)row0 * VT_LD + slot0 * 8);
      vr1 = *(const uint4*)(vp + (size_t)row1 * VT_LD + slot1 * 8);
    }

    // S^T: A = K rows, B = Q rows. keys = c*16+quad*4+r, q = l16.
    f32x4 sc[4] = {};
#pragma unroll
    for (int c = 0; c < 4; ++c)
#pragma unroll
      for (int t = 0; t < 2; ++t) {
        bf16x8 kb = *(const bf16x8*)(Ks + (c * 16 + l16) * 72 + t * 32 + quad * 8);
        sc[c] = mfma16(kb, qf[t], sc[c]);
      }

#pragma unroll
    for (int c = 0; c < 4; ++c) {
      float p0 = fast_exp2(sc[c][0] * SCEXP);
      float p1 = fast_exp2(sc[c][1] * SCEXP);
      float p2 = fast_exp2(sc[c][2] * SCEXP);
      float p3 = fast_exp2(sc[c][3] * SCEXP);
      lsum += (p0 + p1) + (p2 + p3);
      union { unsigned u[2]; } pk;
      pk.u[0] = pack2(p0, p1);
      pk.u[1] = pack2(p2, p3);
      *(uint2*)(Pw + l16 * 72 + c * 16 + quad * 4) = *(uint2*)pk.u;
    }
    __builtin_amdgcn_wave_barrier();   // order DS write -> DS read (wave-local)

#pragma unroll
    for (int t2 = 0; t2 < 2; ++t2) {
      bf16x8 pa = *(const bf16x8*)(Pw + l16 * 72 + t2 * 32 + quad * 8);
#pragma unroll
      for (int c2 = 0; c2 < 4; ++c2) {
        bf16x8 vb = *(const bf16x8*)(Vs + (c2 * 16 + l16) * 72 + t2 * 32 + quad * 8);
        O[c2] = mfma16(pa, vb, O[c2]);
      }
    }
    __syncthreads();
  }

  lsum += __shfl_xor(lsum, 16);
  lsum += __shfl_xor(lsum, 32);
#pragma unroll
  for (int r = 0; r < 4; ++r) {
    float lv = __shfl(lsum, quad * 4 + r, 16);
    float inv = 1.0f / lv;
#pragma unroll
    for (int c2 = 0; c2 < 4; ++c2)
      Aout[(size_t)(token0 + quad * 4 + r) * DMODEL + h * HD + c2 * 16 + l16] =
          f2bf(O[c2][r] * inv);
  }
}

// ---------------- launch ----------------
extern "C" void kernel_launch(void* const* d_in, const int* in_sizes, int n_in,
                              void* d_out, int out_size, void* d_ws, size_t ws_size,
                              hipStream_t stream) {
  const float* queries = (const float*)d_in[0];
  const float* keys    = (const float*)d_in[1];
  const float* values  = (const float*)d_in[2];
  const float* Wq = (const float*)d_in[3];
  const float* bq = (const float*)d_in[4];
  const float* Wk = (const float*)d_in[5];
  const float* bk = (const float*)d_in[6];
  const float* Wv = (const float*)d_in[7];
  const float* bv = (const float*)d_in[8];
  const float* Wo = (const float*)d_in[9];
  const float* bo = (const float*)d_in[10];
  const float* mk = (const float*)d_in[11];
  const float* mv = (const float*)d_in[12];

  unsigned short* ws = (unsigned short*)d_ws;
  unsigned short* Qin  = ws + OF_QIN;
  unsigned short* Kin  = ws + OF_KIN;
  unsigned short* Vin  = ws + OF_VIN;
  unsigned short* Wqt  = ws + OF_WQT;
  unsigned short* Wkt  = ws + OF_WKT;
  unsigned short* Wvt  = ws + OF_WVT;
  unsigned short* Wot  = ws + OF_WOT;
  unsigned short* Qbp  = ws + OF_QB;
  unsigned short* Kprp = ws + OF_KPR;
  unsigned short* Kmm  = ws + OF_KMEM;
  unsigned short* VtGp = ws + OF_VTG;
  unsigned short* Aoutp = ws + OF_AOUT;

  prep_all<<<8832, 256, 0, stream>>>(queries, keys, values, Wq, Wk, Wv, Wo, mk, mv,
                                     Qin, Kin, Vin, Wqt, Wkt, Wvt, Wot, Kmm, VtGp);

  proj_qkv<<<1536, 256, 0, stream>>>(Qin, Kin, Vin, Wqt, Wkt, Wvt, bq, bk, bv,
                                     Qbp, Kprp, VtGp);

  attn_kernel<<<1024, 256, 0, stream>>>(Qbp, Kprp, Kmm, VtGp, Aoutp);

  gemm_out<<<512, 256, 0, stream>>>(Aoutp, Wot, bo, (float*)d_out);
}

// Round 8
// 216.988 us; speedup vs baseline: 1.1324x; 1.0042x over previous
//
#include <hip/hip_runtime.h>

typedef __attribute__((ext_vector_type(8))) __bf16 bf16x8;
typedef __attribute__((ext_vector_type(4))) float f32x4;

#define DEVINL __device__ __forceinline__

constexpr int BZ = 4;
constexpr int SEQ = 1024;
constexpr int DMODEL = 1024;
constexpr int NH = 16;
constexpr int HD = 64;               // dk = dv = 64
constexpr int MSLOT = 128;
constexpr int NT = BZ * SEQ;         // 4096 tokens
constexpr int SKM = SEQ + MSLOT;     // 1152 keys per batch
constexpr int VT_LD = BZ * SKM;      // 4608: leading dim of global V^T
constexpr float SCALE_M = 11.313708498984761f;   // sqrt(128)
constexpr float SCEXP = 0.18033688011112042f;    // (1/sqrt(dk)) * log2(e), folded into Q
// workspace offsets in bf16 (ushort) elements
constexpr size_t OF_QIN  = 0;
constexpr size_t OF_KIN  = OF_QIN  + (size_t)NT * DMODEL;
constexpr size_t OF_VIN  = OF_KIN  + (size_t)NT * DMODEL;
constexpr size_t OF_WQT  = OF_VIN  + (size_t)NT * DMODEL;
constexpr size_t OF_WKT  = OF_WQT  + (size_t)DMODEL * DMODEL;
constexpr size_t OF_WVT  = OF_WKT  + (size_t)DMODEL * DMODEL;
constexpr size_t OF_WOT  = OF_WVT  + (size_t)DMODEL * DMODEL;
constexpr size_t OF_QB   = OF_WOT  + (size_t)DMODEL * DMODEL;
constexpr size_t OF_KPR  = OF_QB   + (size_t)NT * DMODEL;
constexpr size_t OF_KMEM = OF_KPR  + (size_t)NT * DMODEL;
constexpr size_t OF_VTG  = OF_KMEM + (size_t)MSLOT * DMODEL;
constexpr size_t OF_AOUT = OF_VTG  + (size_t)DMODEL * VT_LD;

DEVINL unsigned short f2bf(float f) {
  union { float f; unsigned u; } v; v.f = f;
  unsigned r = v.u + 0x7FFF + ((v.u >> 16) & 1);   // RNE
  return (unsigned short)(r >> 16);
}

#if __has_builtin(__builtin_amdgcn_cvt_pk_bf16_f32)
DEVINL unsigned pack2(float a, float b) {
  auto t = __builtin_amdgcn_cvt_pk_bf16_f32(a, b);
  unsigned r; __builtin_memcpy(&r, &t, 4); return r;
}
#else
DEVINL unsigned pack2(float a, float b) {
  return (unsigned)f2bf(a) | ((unsigned)f2bf(b) << 16);
}
#endif

#if __has_builtin(__builtin_amdgcn_exp2f)
DEVINL float fast_exp2(float x) { return __builtin_amdgcn_exp2f(x); }
#else
DEVINL float fast_exp2(float x) { return exp2f(x); }
#endif

DEVINL f32x4 mfma16(bf16x8 a, bf16x8 b, f32x4 c) {
  return __builtin_amdgcn_mfma_f32_16x16x32_bf16(a, b, c, 0, 0, 0);
}

// async global -> LDS, 16 bytes per lane (global_load_lds_dwordx4)
DEVINL void gload16(const unsigned short* gp, unsigned short* lp) {
  __builtin_amdgcn_global_load_lds(
      (const __attribute__((address_space(1))) unsigned int*)(const void*)gp,
      (__attribute__((address_space(3))) unsigned int*)(void*)lp, 16, 0, 0);
}

// ---------------- merged prep kernel ----------------
__global__ __launch_bounds__(256) void prep_all(
    const float* __restrict__ q, const float* __restrict__ k, const float* __restrict__ v,
    const float* __restrict__ W0, const float* __restrict__ W1,
    const float* __restrict__ W2, const float* __restrict__ W3,
    const float* __restrict__ mk, const float* __restrict__ mv,
    unsigned short* __restrict__ dq, unsigned short* __restrict__ dk,
    unsigned short* __restrict__ dv,
    unsigned short* __restrict__ d0, unsigned short* __restrict__ d1,
    unsigned short* __restrict__ d2, unsigned short* __restrict__ d3,
    unsigned short* __restrict__ Kmm, unsigned short* __restrict__ VtG) {
  __shared__ float t[32][65];
  const int tid = threadIdx.x;
  const int bid = blockIdx.x;
  if (bid < 6144) {
    const int tz = bid >> 11;
    const float* src = (tz == 0) ? q : (tz == 1) ? k : v;
    unsigned short* dst = (tz == 0) ? dq : (tz == 1) ? dk : dv;
    int i = ((bid & 2047) * 256 + tid) * 8;
    float4 v0 = *(const float4*)(src + i);
    float4 v1 = *(const float4*)(src + i + 4);
    union { unsigned u2[4]; uint4 v; } o;
    o.u2[0] = pack2(v0.x, v0.y); o.u2[1] = pack2(v0.z, v0.w);
    o.u2[2] = pack2(v1.x, v1.y); o.u2[3] = pack2(v1.z, v1.w);
    *(uint4*)(dst + i) = o.v;
  } else if (bid < 8192) {
    const int rel = bid - 6144;
    const int z = rel >> 9, rem = rel & 511;
    const float* src = (z == 0) ? W0 : (z == 1) ? W1 : (z == 2) ? W2 : W3;
    unsigned short* dst = (z == 0) ? d0 : (z == 1) ? d1 : (z == 2) ? d2 : d3;
    const int n0 = (rem & 31) * 32, k0 = (rem >> 5) * 64;
    {
      int c = tid & 31, rg = tid >> 5;
#pragma unroll
      for (int rr = 0; rr < 8; ++rr)
        t[c][rg * 8 + rr] = src[(size_t)(k0 + rg * 8 + rr) * DMODEL + n0 + c];
    }
    __syncthreads();
    {
      int n = tid >> 3, ck = tid & 7;
      union { unsigned short u[8]; uint4 v; } o;
#pragma unroll
      for (int j = 0; j < 8; ++j) o.u[j] = f2bf(t[n][ck * 8 + j]);
      *(uint4*)(dst + (size_t)(n0 + n) * DMODEL + k0 + ck * 8) = o.v;
    }
  } else if (bid < 8704) {
    int i = (bid - 8192) * 256 + tid;
    Kmm[i] = f2bf(mk[i] * SCALE_M);
  } else {
    const int rel = bid - 8704;
    const int j0 = (rel & 3) * 32, c0 = (rel >> 2) * 32;
    const int tx = tid & 31, ty = tid >> 5;
#pragma unroll
    for (int r = 0; r < 4; ++r)
      t[ty + r * 8][tx] = mv[(size_t)(j0 + ty + r * 8) * DMODEL + c0 + tx];
    __syncthreads();
#pragma unroll
    for (int r = 0; r < 4; ++r) {
      int c = c0 + ty + r * 8;
      unsigned short vv = f2bf(t[tx][ty + r * 8] * SCALE_M);
#pragma unroll
      for (int bb = 0; bb < BZ; ++bb)
        VtG[(size_t)c * VT_LD + bb * SKM + SEQ + j0 + tx] = vv;
    }
  }
}

// ---------------- GEMM core (BK=64, split column-half buffers, BM=128 BN=64) ----

DEVINL void gemm_stage(const unsigned short* big, const unsigned short* sm,
                       unsigned short* B0, unsigned short* B1,
                       unsigned short* S0, unsigned short* S1,
                       int k0, int tid) {
#pragma unroll
  for (int hb = 0; hb < 2; ++hb) {
    unsigned short* bl = hb ? B1 : B0;
#pragma unroll
    for (int gi = 0; gi < 2; ++gi) {
      int g = gi * 256 + tid;
      int row = g >> 2, slot = g & 3;
      gload16(big + (size_t)row * DMODEL + k0 + hb * 32 + slot * 8, bl + g * 8);
    }
    unsigned short* sl = hb ? S1 : S0;
    int row = tid >> 2, slot = tid & 3;
    gload16(sm + (size_t)row * DMODEL + k0 + hb * 32 + slot * 8, sl + tid * 8);
  }
}

DEVINL void gemm_compute(const unsigned short* B0, const unsigned short* B1,
                         const unsigned short* S0, const unsigned short* S1,
                         int wr, int wc, int quad, int l16, f32x4 acc[4][2]) {
#pragma unroll
  for (int hb = 0; hb < 2; ++hb) {
    const unsigned short* bl = hb ? B1 : B0;
    const unsigned short* sl = hb ? S1 : S0;
    bf16x8 af[4], bfr[2];
#pragma unroll
    for (int rb = 0; rb < 4; ++rb)
      af[rb] = *(const bf16x8*)(bl + (wr * 64 + rb * 16 + l16) * 32 + quad * 8);
#pragma unroll
    for (int cb = 0; cb < 2; ++cb)
      bfr[cb] = *(const bf16x8*)(sl + (wc * 32 + cb * 16 + l16) * 32 + quad * 8);
#pragma unroll
    for (int rb = 0; rb < 4; ++rb)
#pragma unroll
      for (int cb = 0; cb < 2; ++cb)
        acc[rb][cb] = mfma16(af[rb], bfr[cb], acc[rb][cb]);
  }
}

// merged Q/K/V projections. Q output pre-scaled by SCEXP (folded softmax scale).
__global__ __launch_bounds__(256) void proj_qkv(
    const unsigned short* __restrict__ Qin, const unsigned short* __restrict__ Kin,
    const unsigned short* __restrict__ Vin, const unsigned short* __restrict__ Wqt,
    const unsigned short* __restrict__ Wkt, const unsigned short* __restrict__ Wvt,
    const float* __restrict__ bq, const float* __restrict__ bk,
    const float* __restrict__ bv, unsigned short* __restrict__ Qbp,
    unsigned short* __restrict__ Kprp, unsigned short* __restrict__ VtG) {
  __shared__ unsigned short Big0[128 * 32], Big1[128 * 32];
  __shared__ unsigned short Sm0[64 * 32], Sm1[64 * 32];
  const int tid = threadIdx.x;
  const int pid = blockIdx.x >> 9;
  const int idx = blockIdx.x & 511;
  const int w = tid >> 6, lane = tid & 63, quad = lane >> 4, l16 = lane & 15;
  const int wr = w >> 1, wc = w & 1;
  f32x4 acc[4][2] = {};

  if (pid < 2) {
    const unsigned short* A  = pid ? Kin : Qin;
    const unsigned short* Wt = pid ? Wkt : Wqt;
    const float* bias        = pid ? bk : bq;
    unsigned short* out      = pid ? Kprp : Qbp;
    const float osc          = pid ? 1.0f : SCEXP;
    const int m0 = (idx & 31) * 128, n0 = (idx >> 5) * 64;   // bid%8 = m%8
    const unsigned short* big = A + (size_t)m0 * DMODEL;
    const unsigned short* sm  = Wt + (size_t)n0 * DMODEL;
    for (int kt = 0; kt < 16; ++kt) {
      gemm_stage(big, sm, Big0, Big1, Sm0, Sm1, kt * 64, tid);
      __syncthreads();
      gemm_compute(Big0, Big1, Sm0, Sm1, wr, wc, quad, l16, acc);
      __syncthreads();
    }
#pragma unroll
    for (int rb = 0; rb < 4; ++rb)
#pragma unroll
      for (int cb = 0; cb < 2; ++cb)
#pragma unroll
        for (int r = 0; r < 4; ++r) {
          int row = m0 + wr * 64 + rb * 16 + quad * 4 + r;
          int col = n0 + wc * 32 + cb * 16 + l16;
          out[(size_t)row * DMODEL + col] = f2bf((acc[rb][cb][r] + bias[col]) * osc);
        }
  } else {
    const int t0 = (idx & 63) * 64, n0 = (idx >> 6) * 128;
    const unsigned short* big = Wvt + (size_t)n0 * DMODEL;   // n rows
    const unsigned short* sm  = Vin + (size_t)t0 * DMODEL;   // token rows
    for (int kt = 0; kt < 16; ++kt) {
      gemm_stage(big, sm, Big0, Big1, Sm0, Sm1, kt * 64, tid);
      __syncthreads();
      gemm_compute(Big0, Big1, Sm0, Sm1, wr, wc, quad, l16, acc);
      __syncthreads();
    }
#pragma unroll
    for (int rb = 0; rb < 4; ++rb)
#pragma unroll
      for (int cb = 0; cb < 2; ++cb)
#pragma unroll
        for (int r = 0; r < 4; ++r) {
          int n = n0 + wr * 64 + rb * 16 + quad * 4 + r;
          int tok = t0 + wc * 32 + cb * 16 + l16;
          int col = tok + (tok >> 10) * MSLOT;
          VtG[(size_t)n * VT_LD + col] = f2bf(acc[rb][cb][r] + bv[n]);
        }
  }
}

// output GEMM, BK=64 split-buffer, activation-co-located (bid%8 = m%8)
__global__ __launch_bounds__(256) void gemm_out(const unsigned short* __restrict__ A,
                                                const unsigned short* __restrict__ Wt,
                                                const float* __restrict__ bias,
                                                float* __restrict__ Cout) {
  __shared__ unsigned short Big0[128 * 32], Big1[128 * 32];
  __shared__ unsigned short Sm0[64 * 32], Sm1[64 * 32];
  const int tid = threadIdx.x;
  const int idx = blockIdx.x;
  const int m0 = (idx & 31) * 128, n0 = (idx >> 5) * 64;    // bid%8 = m%8
  const int w = tid >> 6, lane = tid & 63, quad = lane >> 4, l16 = lane & 15;
  const int wr = w >> 1, wc = w & 1;
  f32x4 acc[4][2] = {};
  const unsigned short* big = A + (size_t)m0 * DMODEL;
  const unsigned short* sm  = Wt + (size_t)n0 * DMODEL;
  for (int kt = 0; kt < 16; ++kt) {
    gemm_stage(big, sm, Big0, Big1, Sm0, Sm1, kt * 64, tid);
    __syncthreads();
    gemm_compute(Big0, Big1, Sm0, Sm1, wr, wc, quad, l16, acc);
    __syncthreads();
  }
#pragma unroll
  for (int rb = 0; rb < 4; ++rb)
#pragma unroll
    for (int cb = 0; cb < 2; ++cb)
#pragma unroll
      for (int r = 0; r < 4; ++r) {
        int row = m0 + wr * 64 + rb * 16 + quad * 4 + r;
        int col = n0 + wc * 32 + cb * 16 + l16;
        Cout[(size_t)row * DMODEL + col] = acc[rb][cb][r] + bias[col];
      }
}

// ---------------- flash attention v3 ----------------
// 64 q/block, swizzle bid = qb*64 + bh (K/V co-located per XCD — verified R7).
// XOR-swizzled stride-64 LDS (16B granule g of row r stored at g^(r&7)):
// all staging writes / K,V,P reads-writes become <=2-way bank aliased (free).
// Double-buffered K/V -> ONE __syncthreads per tile. LDS 40KB -> 4 blocks/CU.
// Q pre-scaled by SCEXP at proj -> exp2 directly on MFMA output.
__global__ __launch_bounds__(256) void attn_kernel(const unsigned short* __restrict__ Qb,
                                                   const unsigned short* __restrict__ Kproj,
                                                   const unsigned short* __restrict__ Kmem,
                                                   const unsigned short* __restrict__ VtG,
                                                   unsigned short* __restrict__ Aout) {
  __shared__ unsigned short Ks[2][64 * 64];
  __shared__ unsigned short Vs[2][64 * 64];
  __shared__ unsigned short Pl[4 * 16 * 64];    // per-wave P[q][key], same swizzle
  const int tid = threadIdx.x;
  const int bh = blockIdx.x & 63, qb = blockIdx.x >> 6;
  const int b = bh & 3, h = bh >> 2;
  const int w = tid >> 6, lane = tid & 63, quad = lane >> 4, l16 = lane & 15;
  const int token0 = b * SEQ + qb * 64 + w * 16;
  unsigned short* Pw = Pl + w * 16 * 64;
  const int lx = l16 & 7;                       // row&7 for swizzle (rows differ by 16)

  const int row0 = tid >> 3, slot0 = tid & 7;
  const int g1 = tid + 256;
  const int row1 = g1 >> 3, slot1 = g1 & 7;
  const int loff0 = row0 * 64 + (slot0 ^ (row0 & 7)) * 8;   // swizzled staging offsets
  const int loff1 = row1 * 64 + (slot1 ^ (row1 & 7)) * 8;

  auto kbase = [&](int tile) -> const unsigned short* {
    return (tile < 16) ? Kproj + (size_t)(b * SEQ + tile * 64) * DMODEL + h * HD
                       : Kmem + (size_t)((tile - 16) * 64) * DMODEL + h * HD;
  };
  auto vbase = [&](int tile) -> const unsigned short* {
    int c0 = (tile < 16) ? b * SKM + tile * 64 : b * SKM + SEQ + (tile - 16) * 64;
    return VtG + (size_t)(h * HD) * VT_LD + c0;
  };

  bf16x8 qf[2];   // B-operand: Q[n=l16][k = quad*8+j (+32t)] (pre-scaled by SCEXP)
#pragma unroll
  for (int t = 0; t < 2; ++t)
    qf[t] = *(const bf16x8*)(Qb + (size_t)(token0 + l16) * DMODEL + h * HD + t * 32 + quad * 8);

  f32x4 O[4] = {};
  float lsum = 0.0f;

  uint4 kr0, kr1, vr0, vr1;
  {
    const unsigned short* kp = kbase(0);
    const unsigned short* vp = vbase(0);
    kr0 = *(const uint4*)(kp + (size_t)row0 * DMODEL + slot0 * 8);
    kr1 = *(const uint4*)(kp + (size_t)row1 * DMODEL + slot1 * 8);
    vr0 = *(const uint4*)(vp + (size_t)row0 * VT_LD + slot0 * 8);
    vr1 = *(const uint4*)(vp + (size_t)row1 * VT_LD + slot1 * 8);
  }
  *(uint4*)(Ks[0] + loff0) = kr0;
  *(uint4*)(Ks[0] + loff1) = kr1;
  *(uint4*)(Vs[0] + loff0) = vr0;
  *(uint4*)(Vs[0] + loff1) = vr1;
  __syncthreads();

  for (int tile = 0; tile < 18; ++tile) {
    const int cur = tile & 1;
    if (tile < 17) {   // issue next tile's global loads; consumed at end of iter
      const unsigned short* kp = kbase(tile + 1);
      const unsigned short* vp = vbase(tile + 1);
      kr0 = *(const uint4*)(kp + (size_t)row0 * DMODEL + slot0 * 8);
      kr1 = *(const uint4*)(kp + (size_t)row1 * DMODEL + slot1 * 8);
      vr0 = *(const uint4*)(vp + (size_t)row0 * VT_LD + slot0 * 8);
      vr1 = *(const uint4*)(vp + (size_t)row1 * VT_LD + slot1 * 8);
    }

    // S^T: A = K rows, B = Q rows. keys = c*16+quad*4+r, q = l16.
    f32x4 sc[4] = {};
#pragma unroll
    for (int c = 0; c < 4; ++c)
#pragma unroll
      for (int t = 0; t < 2; ++t) {
        bf16x8 kb = *(const bf16x8*)(Ks[cur] + (c * 16 + l16) * 64 +
                                     ((t * 4 + quad) ^ lx) * 8);
        sc[c] = mfma16(kb, qf[t], sc[c]);
      }

#pragma unroll
    for (int c = 0; c < 4; ++c) {
      float p0 = fast_exp2(sc[c][0]);
      float p1 = fast_exp2(sc[c][1]);
      float p2 = fast_exp2(sc[c][2]);
      float p3 = fast_exp2(sc[c][3]);
      lsum += (p0 + p1) + (p2 + p3);
      union { unsigned u[2]; } pk;
      pk.u[0] = pack2(p0, p1);
      pk.u[1] = pack2(p2, p3);
      // P[q=l16][key=c*16+quad*4..+3]: granule 2c+(quad>>1), swizzled, +4 ushorts if quad odd
      *(uint2*)(Pw + l16 * 64 + ((2 * c + (quad >> 1)) ^ lx) * 8 + (quad & 1) * 4) =
          *(uint2*)pk.u;
    }
    __builtin_amdgcn_wave_barrier();   // order DS write -> DS read (wave-local)

#pragma unroll
    for (int t2 = 0; t2 < 2; ++t2) {
      bf16x8 pa = *(const bf16x8*)(Pw + l16 * 64 + ((t2 * 4 + quad) ^ lx) * 8);
#pragma unroll
      for (int c2 = 0; c2 < 4; ++c2) {
        bf16x8 vb = *(const bf16x8*)(Vs[cur] + (c2 * 16 + l16) * 64 +
                                     ((t2 * 4 + quad) ^ lx) * 8);
        O[c2] = mfma16(pa, vb, O[c2]);
      }
    }

    if (tile < 17) {   // stage next tile into the other buffer (safe: barrier t-1 passed)
      *(uint4*)(Ks[cur ^ 1] + loff0) = kr0;
      *(uint4*)(Ks[cur ^ 1] + loff1) = kr1;
      *(uint4*)(Vs[cur ^ 1] + loff0) = vr0;
      *(uint4*)(Vs[cur ^ 1] + loff1) = vr1;
    }
    __syncthreads();
  }

  lsum += __shfl_xor(lsum, 16);
  lsum += __shfl_xor(lsum, 32);
#pragma unroll
  for (int r = 0; r < 4; ++r) {
    float lv = __shfl(lsum, quad * 4 + r, 16);
    float inv = 1.0f / lv;
#pragma unroll
    for (int c2 = 0; c2 < 4; ++c2)
      Aout[(size_t)(token0 + quad * 4 + r) * DMODEL + h * HD + c2 * 16 + l16] =
          f2bf(O[c2][r] * inv);
  }
}

// ---------------- launch ----------------
extern "C" void kernel_launch(void* const* d_in, const int* in_sizes, int n_in,
                              void* d_out, int out_size, void* d_ws, size_t ws_size,
                              hipStream_t stream) {
  const float* queries = (const float*)d_in[0];
  const float* keys    = (const float*)d_in[1];
  const float* values  = (const float*)d_in[2];
  const float* Wq = (const float*)d_in[3];
  const float* bq = (const float*)d_in[4];
  const float* Wk = (const float*)d_in[5];
  const float* bk = (const float*)d_in[6];
  const float* Wv = (const float*)d_in[7];
  const float* bv = (const float*)d_in[8];
  const float* Wo = (const float*)d_in[9];
  const float* bo = (const float*)d_in[10];
  const float* mk = (const float*)d_in[11];
  const float* mv = (const float*)d_in[12];

  unsigned short* ws = (unsigned short*)d_ws;
  unsigned short* Qin  = ws + OF_QIN;
  unsigned short* Kin  = ws + OF_KIN;
  unsigned short* Vin  = ws + OF_VIN;
  unsigned short* Wqt  = ws + OF_WQT;
  unsigned short* Wkt  = ws + OF_WKT;
  unsigned short* Wvt  = ws + OF_WVT;
  unsigned short* Wot  = ws + OF_WOT;
  unsigned short* Qbp  = ws + OF_QB;
  unsigned short* Kprp = ws + OF_KPR;
  unsigned short* Kmm  = ws + OF_KMEM;
  unsigned short* VtGp = ws + OF_VTG;
  unsigned short* Aoutp = ws + OF_AOUT;

  prep_all<<<8832, 256, 0, stream>>>(queries, keys, values, Wq, Wk, Wv, Wo, mk, mv,
                                     Qin, Kin, Vin, Wqt, Wkt, Wvt, Wot, Kmm, VtGp);

  proj_qkv<<<1536, 256, 0, stream>>>(Qin, Kin, Vin, Wqt, Wkt, Wvt, bq, bk, bv,
                                     Qbp, Kprp, VtGp);

  attn_kernel<<<1024, 256, 0, stream>>>(Qbp, Kprp, Kmm, VtGp, Aoutp);

  gemm_out<<<512, 256, 0, stream>>>(Aoutp, Wot, bo, (float*)d_out);
}

// Round 9
// 213.595 us; speedup vs baseline: 1.1504x; 1.0159x over previous
//
#include <hip/hip_runtime.h>

typedef __attribute__((ext_vector_type(8))) __bf16 bf16x8;
typedef __attribute__((ext_vector_type(4))) float f32x4;

#define DEVINL __device__ __forceinline__

constexpr int BZ = 4;
constexpr int SEQ = 1024;
constexpr int DMODEL = 1024;
constexpr int NH = 16;
constexpr int HD = 64;               // dk = dv = 64
constexpr int MSLOT = 128;
constexpr int NT = BZ * SEQ;         // 4096 tokens
constexpr int SKM = SEQ + MSLOT;     // 1152 keys per batch
constexpr int VT_LD = BZ * SKM;      // 4608: leading dim of global V^T
constexpr float SCALE_M = 11.313708498984761f;   // sqrt(128)
constexpr float SCEXP = 0.18033688011112042f;    // (1/sqrt(dk)) * log2(e), folded into Q
// workspace offsets in bf16 (ushort) elements
constexpr size_t OF_QIN  = 0;
constexpr size_t OF_KIN  = OF_QIN  + (size_t)NT * DMODEL;
constexpr size_t OF_VIN  = OF_KIN  + (size_t)NT * DMODEL;
constexpr size_t OF_WQT  = OF_VIN  + (size_t)NT * DMODEL;
constexpr size_t OF_WKT  = OF_WQT  + (size_t)DMODEL * DMODEL;
constexpr size_t OF_WVT  = OF_WKT  + (size_t)DMODEL * DMODEL;
constexpr size_t OF_WOT  = OF_WVT  + (size_t)DMODEL * DMODEL;
constexpr size_t OF_QB   = OF_WOT  + (size_t)DMODEL * DMODEL;
constexpr size_t OF_KPR  = OF_QB   + (size_t)NT * DMODEL;
constexpr size_t OF_KMEM = OF_KPR  + (size_t)NT * DMODEL;
constexpr size_t OF_VTG  = OF_KMEM + (size_t)MSLOT * DMODEL;
constexpr size_t OF_AOUT = OF_VTG  + (size_t)DMODEL * VT_LD;

DEVINL unsigned short f2bf(float f) {
  union { float f; unsigned u; } v; v.f = f;
  unsigned r = v.u + 0x7FFF + ((v.u >> 16) & 1);   // RNE
  return (unsigned short)(r >> 16);
}

#if __has_builtin(__builtin_amdgcn_cvt_pk_bf16_f32)
DEVINL unsigned pack2(float a, float b) {
  auto t = __builtin_amdgcn_cvt_pk_bf16_f32(a, b);
  unsigned r; __builtin_memcpy(&r, &t, 4); return r;
}
#else
DEVINL unsigned pack2(float a, float b) {
  return (unsigned)f2bf(a) | ((unsigned)f2bf(b) << 16);
}
#endif

#if __has_builtin(__builtin_amdgcn_exp2f)
DEVINL float fast_exp2(float x) { return __builtin_amdgcn_exp2f(x); }
#else
DEVINL float fast_exp2(float x) { return exp2f(x); }
#endif

DEVINL f32x4 mfma16(bf16x8 a, bf16x8 b, f32x4 c) {
  return __builtin_amdgcn_mfma_f32_16x16x32_bf16(a, b, c, 0, 0, 0);
}

// async global -> LDS, 16 bytes per lane (global_load_lds_dwordx4)
DEVINL void gload16(const unsigned short* gp, unsigned short* lp) {
  __builtin_amdgcn_global_load_lds(
      (const __attribute__((address_space(1))) unsigned int*)(const void*)gp,
      (__attribute__((address_space(3))) unsigned int*)(void*)lp, 16, 0, 0);
}

// ---------------- merged prep kernel ----------------
__global__ __launch_bounds__(256) void prep_all(
    const float* __restrict__ q, const float* __restrict__ k, const float* __restrict__ v,
    const float* __restrict__ W0, const float* __restrict__ W1,
    const float* __restrict__ W2, const float* __restrict__ W3,
    const float* __restrict__ mk, const float* __restrict__ mv,
    unsigned short* __restrict__ dq, unsigned short* __restrict__ dk,
    unsigned short* __restrict__ dv,
    unsigned short* __restrict__ d0, unsigned short* __restrict__ d1,
    unsigned short* __restrict__ d2, unsigned short* __restrict__ d3,
    unsigned short* __restrict__ Kmm, unsigned short* __restrict__ VtG) {
  __shared__ float t[32][65];
  const int tid = threadIdx.x;
  const int bid = blockIdx.x;
  if (bid < 6144) {
    const int tz = bid >> 11;
    const float* src = (tz == 0) ? q : (tz == 1) ? k : v;
    unsigned short* dst = (tz == 0) ? dq : (tz == 1) ? dk : dv;
    int i = ((bid & 2047) * 256 + tid) * 8;
    float4 v0 = *(const float4*)(src + i);
    float4 v1 = *(const float4*)(src + i + 4);
    union { unsigned u2[4]; uint4 v; } o;
    o.u2[0] = pack2(v0.x, v0.y); o.u2[1] = pack2(v0.z, v0.w);
    o.u2[2] = pack2(v1.x, v1.y); o.u2[3] = pack2(v1.z, v1.w);
    *(uint4*)(dst + i) = o.v;
  } else if (bid < 8192) {
    const int rel = bid - 6144;
    const int z = rel >> 9, rem = rel & 511;
    const float* src = (z == 0) ? W0 : (z == 1) ? W1 : (z == 2) ? W2 : W3;
    unsigned short* dst = (z == 0) ? d0 : (z == 1) ? d1 : (z == 2) ? d2 : d3;
    const int n0 = (rem & 31) * 32, k0 = (rem >> 5) * 64;
    {
      int c = tid & 31, rg = tid >> 5;
#pragma unroll
      for (int rr = 0; rr < 8; ++rr)
        t[c][rg * 8 + rr] = src[(size_t)(k0 + rg * 8 + rr) * DMODEL + n0 + c];
    }
    __syncthreads();
    {
      int n = tid >> 3, ck = tid & 7;
      union { unsigned short u[8]; uint4 v; } o;
#pragma unroll
      for (int j = 0; j < 8; ++j) o.u[j] = f2bf(t[n][ck * 8 + j]);
      *(uint4*)(dst + (size_t)(n0 + n) * DMODEL + k0 + ck * 8) = o.v;
    }
  } else if (bid < 8704) {
    int i = (bid - 8192) * 256 + tid;
    Kmm[i] = f2bf(mk[i] * SCALE_M);
  } else {
    const int rel = bid - 8704;
    const int j0 = (rel & 3) * 32, c0 = (rel >> 2) * 32;
    const int tx = tid & 31, ty = tid >> 5;
#pragma unroll
    for (int r = 0; r < 4; ++r)
      t[ty + r * 8][tx] = mv[(size_t)(j0 + ty + r * 8) * DMODEL + c0 + tx];
    __syncthreads();
#pragma unroll
    for (int r = 0; r < 4; ++r) {
      int c = c0 + ty + r * 8;
      unsigned short vv = f2bf(t[tx][ty + r * 8] * SCALE_M);
#pragma unroll
      for (int bb = 0; bb < BZ; ++bb)
        VtG[(size_t)c * VT_LD + bb * SKM + SEQ + j0 + tx] = vv;
    }
  }
}

// ---------------- GEMM core (BK=64, split column-half buffers, BM=128 BN=64) ----

DEVINL void gemm_stage(const unsigned short* big, const unsigned short* sm,
                       unsigned short* B0, unsigned short* B1,
                       unsigned short* S0, unsigned short* S1,
                       int k0, int tid) {
#pragma unroll
  for (int hb = 0; hb < 2; ++hb) {
    unsigned short* bl = hb ? B1 : B0;
#pragma unroll
    for (int gi = 0; gi < 2; ++gi) {
      int g = gi * 256 + tid;
      int row = g >> 2, slot = g & 3;
      gload16(big + (size_t)row * DMODEL + k0 + hb * 32 + slot * 8, bl + g * 8);
    }
    unsigned short* sl = hb ? S1 : S0;
    int row = tid >> 2, slot = tid & 3;
    gload16(sm + (size_t)row * DMODEL + k0 + hb * 32 + slot * 8, sl + tid * 8);
  }
}

DEVINL void gemm_compute(const unsigned short* B0, const unsigned short* B1,
                         const unsigned short* S0, const unsigned short* S1,
                         int wr, int wc, int quad, int l16, f32x4 acc[4][2]) {
#pragma unroll
  for (int hb = 0; hb < 2; ++hb) {
    const unsigned short* bl = hb ? B1 : B0;
    const unsigned short* sl = hb ? S1 : S0;
    bf16x8 af[4], bfr[2];
#pragma unroll
    for (int rb = 0; rb < 4; ++rb)
      af[rb] = *(const bf16x8*)(bl + (wr * 64 + rb * 16 + l16) * 32 + quad * 8);
#pragma unroll
    for (int cb = 0; cb < 2; ++cb)
      bfr[cb] = *(const bf16x8*)(sl + (wc * 32 + cb * 16 + l16) * 32 + quad * 8);
#pragma unroll
    for (int rb = 0; rb < 4; ++rb)
#pragma unroll
      for (int cb = 0; cb < 2; ++cb)
        acc[rb][cb] = mfma16(af[rb], bfr[cb], acc[rb][cb]);
  }
}

// merged Q/K/V projections. Q output pre-scaled by SCEXP (folded softmax scale).
__global__ __launch_bounds__(256) void proj_qkv(
    const unsigned short* __restrict__ Qin, const unsigned short* __restrict__ Kin,
    const unsigned short* __restrict__ Vin, const unsigned short* __restrict__ Wqt,
    const unsigned short* __restrict__ Wkt, const unsigned short* __restrict__ Wvt,
    const float* __restrict__ bq, const float* __restrict__ bk,
    const float* __restrict__ bv, unsigned short* __restrict__ Qbp,
    unsigned short* __restrict__ Kprp, unsigned short* __restrict__ VtG) {
  __shared__ unsigned short Big0[128 * 32], Big1[128 * 32];
  __shared__ unsigned short Sm0[64 * 32], Sm1[64 * 32];
  const int tid = threadIdx.x;
  const int pid = blockIdx.x >> 9;
  const int idx = blockIdx.x & 511;
  const int w = tid >> 6, lane = tid & 63, quad = lane >> 4, l16 = lane & 15;
  const int wr = w >> 1, wc = w & 1;
  f32x4 acc[4][2] = {};

  if (pid < 2) {
    const unsigned short* A  = pid ? Kin : Qin;
    const unsigned short* Wt = pid ? Wkt : Wqt;
    const float* bias        = pid ? bk : bq;
    unsigned short* out      = pid ? Kprp : Qbp;
    const float osc          = pid ? 1.0f : SCEXP;
    const int m0 = (idx & 31) * 128, n0 = (idx >> 5) * 64;   // bid%8 = m%8
    const unsigned short* big = A + (size_t)m0 * DMODEL;
    const unsigned short* sm  = Wt + (size_t)n0 * DMODEL;
    for (int kt = 0; kt < 16; ++kt) {
      gemm_stage(big, sm, Big0, Big1, Sm0, Sm1, kt * 64, tid);
      __syncthreads();
      gemm_compute(Big0, Big1, Sm0, Sm1, wr, wc, quad, l16, acc);
      __syncthreads();
    }
#pragma unroll
    for (int rb = 0; rb < 4; ++rb)
#pragma unroll
      for (int cb = 0; cb < 2; ++cb)
#pragma unroll
        for (int r = 0; r < 4; ++r) {
          int row = m0 + wr * 64 + rb * 16 + quad * 4 + r;
          int col = n0 + wc * 32 + cb * 16 + l16;
          out[(size_t)row * DMODEL + col] = f2bf((acc[rb][cb][r] + bias[col]) * osc);
        }
  } else {
    const int t0 = (idx & 63) * 64, n0 = (idx >> 6) * 128;
    const unsigned short* big = Wvt + (size_t)n0 * DMODEL;   // n rows
    const unsigned short* sm  = Vin + (size_t)t0 * DMODEL;   // token rows
    for (int kt = 0; kt < 16; ++kt) {
      gemm_stage(big, sm, Big0, Big1, Sm0, Sm1, kt * 64, tid);
      __syncthreads();
      gemm_compute(Big0, Big1, Sm0, Sm1, wr, wc, quad, l16, acc);
      __syncthreads();
    }
#pragma unroll
    for (int rb = 0; rb < 4; ++rb)
#pragma unroll
      for (int cb = 0; cb < 2; ++cb)
#pragma unroll
        for (int r = 0; r < 4; ++r) {
          int n = n0 + wr * 64 + rb * 16 + quad * 4 + r;
          int tok = t0 + wc * 32 + cb * 16 + l16;
          int col = tok + (tok >> 10) * MSLOT;
          VtG[(size_t)n * VT_LD + col] = f2bf(acc[rb][cb][r] + bv[n]);
        }
  }
}

// output GEMM: BM=64 BN=64 BK=64, 1024 blocks = 4/CU (latency-bound -> more TLP).
// idx&63 = m-tile so bid%8 = m%8 (A-tile consumers share an XCD L2 slice).
__global__ __launch_bounds__(256) void gemm_out(const unsigned short* __restrict__ A,
                                                const unsigned short* __restrict__ Wt,
                                                const float* __restrict__ bias,
                                                float* __restrict__ Cout) {
  __shared__ unsigned short A0[64 * 32], A1[64 * 32];
  __shared__ unsigned short B0[64 * 32], B1[64 * 32];
  const int tid = threadIdx.x;
  const int idx = blockIdx.x;
  const int m0 = (idx & 63) * 64, n0 = (idx >> 6) * 64;    // bid%8 = m%8
  const int w = tid >> 6, lane = tid & 63, quad = lane >> 4, l16 = lane & 15;
  const int wr = w >> 1, wc = w & 1;
  f32x4 acc[2][2] = {};
  const unsigned short* rA = A + (size_t)m0 * DMODEL;
  const unsigned short* rB = Wt + (size_t)n0 * DMODEL;
  const int srow = tid >> 2, sslot = tid & 3;
  for (int kt = 0; kt < 16; ++kt) {
    const int k0 = kt * 64;
    gload16(rA + (size_t)srow * DMODEL + k0 + sslot * 8, A0 + tid * 8);
    gload16(rA + (size_t)srow * DMODEL + k0 + 32 + sslot * 8, A1 + tid * 8);
    gload16(rB + (size_t)srow * DMODEL + k0 + sslot * 8, B0 + tid * 8);
    gload16(rB + (size_t)srow * DMODEL + k0 + 32 + sslot * 8, B1 + tid * 8);
    __syncthreads();
#pragma unroll
    for (int hb = 0; hb < 2; ++hb) {
      const unsigned short* al = hb ? A1 : A0;
      const unsigned short* bl = hb ? B1 : B0;
      bf16x8 af[2], bfr[2];
#pragma unroll
      for (int rb = 0; rb < 2; ++rb)
        af[rb] = *(const bf16x8*)(al + (wr * 32 + rb * 16 + l16) * 32 + quad * 8);
#pragma unroll
      for (int cb = 0; cb < 2; ++cb)
        bfr[cb] = *(const bf16x8*)(bl + (wc * 32 + cb * 16 + l16) * 32 + quad * 8);
#pragma unroll
      for (int rb = 0; rb < 2; ++rb)
#pragma unroll
        for (int cb = 0; cb < 2; ++cb)
          acc[rb][cb] = mfma16(af[rb], bfr[cb], acc[rb][cb]);
    }
    __syncthreads();
  }
#pragma unroll
  for (int rb = 0; rb < 2; ++rb)
#pragma unroll
    for (int cb = 0; cb < 2; ++cb)
#pragma unroll
      for (int r = 0; r < 4; ++r) {
        int row = m0 + wr * 32 + rb * 16 + quad * 4 + r;
        int col = n0 + wc * 32 + cb * 16 + l16;
        Cout[(size_t)row * DMODEL + col] = acc[rb][cb][r] + bias[col];
      }
}

// ---------------- flash attention v4 ----------------
// 64 q/block, swizzle bid = qb*64 + bh (K/V co-located per XCD — verified R7).
// XOR-swizzled stride-64 LDS; double-buffered K/V, one barrier per tile.
// Q pre-scaled by SCEXP. lsum computed by MFMA against a ones B-operand:
// Lacc[r] = sum_k P[q=quad*4+r][k] — no per-tile VALU adds, no epilogue shuffles.
__global__ __launch_bounds__(256) void attn_kernel(const unsigned short* __restrict__ Qb,
                                                   const unsigned short* __restrict__ Kproj,
                                                   const unsigned short* __restrict__ Kmem,
                                                   const unsigned short* __restrict__ VtG,
                                                   unsigned short* __restrict__ Aout) {
  __shared__ unsigned short Ks[2][64 * 64];
  __shared__ unsigned short Vs[2][64 * 64];
  __shared__ unsigned short Pl[4 * 16 * 64];    // per-wave P[q][key], same swizzle
  const int tid = threadIdx.x;
  const int bh = blockIdx.x & 63, qb = blockIdx.x >> 6;
  const int b = bh & 3, h = bh >> 2;
  const int w = tid >> 6, lane = tid & 63, quad = lane >> 4, l16 = lane & 15;
  const int token0 = b * SEQ + qb * 64 + w * 16;
  unsigned short* Pw = Pl + w * 16 * 64;
  const int lx = l16 & 7;                       // row&7 for swizzle (rows differ by 16)

  const int row0 = tid >> 3, slot0 = tid & 7;
  const int g1 = tid + 256;
  const int row1 = g1 >> 3, slot1 = g1 & 7;
  const int loff0 = row0 * 64 + (slot0 ^ (row0 & 7)) * 8;   // swizzled staging offsets
  const int loff1 = row1 * 64 + (slot1 ^ (row1 & 7)) * 8;

  auto kbase = [&](int tile) -> const unsigned short* {
    return (tile < 16) ? Kproj + (size_t)(b * SEQ + tile * 64) * DMODEL + h * HD
                       : Kmem + (size_t)((tile - 16) * 64) * DMODEL + h * HD;
  };
  auto vbase = [&](int tile) -> const unsigned short* {
    int c0 = (tile < 16) ? b * SKM + tile * 64 : b * SKM + SEQ + (tile - 16) * 64;
    return VtG + (size_t)(h * HD) * VT_LD + c0;
  };

  bf16x8 qf[2];   // B-operand: Q[n=l16][k = quad*8+j (+32t)] (pre-scaled by SCEXP)
#pragma unroll
  for (int t = 0; t < 2; ++t)
    qf[t] = *(const bf16x8*)(Qb + (size_t)(token0 + l16) * DMODEL + h * HD + t * 32 + quad * 8);

  bf16x8 ones;
  {
    union { unsigned short u[8]; bf16x8 v; } one8;
#pragma unroll
    for (int i = 0; i < 8; ++i) one8.u[i] = 0x3F80;   // bf16 1.0
    ones = one8.v;
  }

  f32x4 O[4] = {};
  f32x4 Lacc = {};

  uint4 kr0, kr1, vr0, vr1;
  {
    const unsigned short* kp = kbase(0);
    const unsigned short* vp = vbase(0);
    kr0 = *(const uint4*)(kp + (size_t)row0 * DMODEL + slot0 * 8);
    kr1 = *(const uint4*)(kp + (size_t)row1 * DMODEL + slot1 * 8);
    vr0 = *(const uint4*)(vp + (size_t)row0 * VT_LD + slot0 * 8);
    vr1 = *(const uint4*)(vp + (size_t)row1 * VT_LD + slot1 * 8);
  }
  *(uint4*)(Ks[0] + loff0) = kr0;
  *(uint4*)(Ks[0] + loff1) = kr1;
  *(uint4*)(Vs[0] + loff0) = vr0;
  *(uint4*)(Vs[0] + loff1) = vr1;
  __syncthreads();

  for (int tile = 0; tile < 18; ++tile) {
    const int cur = tile & 1;
    if (tile < 17) {   // issue next tile's global loads; consumed at end of iter
      const unsigned short* kp = kbase(tile + 1);
      const unsigned short* vp = vbase(tile + 1);
      kr0 = *(const uint4*)(kp + (size_t)row0 * DMODEL + slot0 * 8);
      kr1 = *(const uint4*)(kp + (size_t)row1 * DMODEL + slot1 * 8);
      vr0 = *(const uint4*)(vp + (size_t)row0 * VT_LD + slot0 * 8);
      vr1 = *(const uint4*)(vp + (size_t)row1 * VT_LD + slot1 * 8);
    }

    // S^T: A = K rows, B = Q rows. keys = c*16+quad*4+r, q = l16.
    f32x4 sc[4] = {};
#pragma unroll
    for (int c = 0; c < 4; ++c)
#pragma unroll
      for (int t = 0; t < 2; ++t) {
        bf16x8 kb = *(const bf16x8*)(Ks[cur] + (c * 16 + l16) * 64 +
                                     ((t * 4 + quad) ^ lx) * 8);
        sc[c] = mfma16(kb, qf[t], sc[c]);
      }

#pragma unroll
    for (int c = 0; c < 4; ++c) {
      float p0 = fast_exp2(sc[c][0]);
      float p1 = fast_exp2(sc[c][1]);
      float p2 = fast_exp2(sc[c][2]);
      float p3 = fast_exp2(sc[c][3]);
      union { unsigned u[2]; } pk;
      pk.u[0] = pack2(p0, p1);
      pk.u[1] = pack2(p2, p3);
      // P[q=l16][key=c*16+quad*4..+3]: granule 2c+(quad>>1), swizzled, +4 ushorts if quad odd
      *(uint2*)(Pw + l16 * 64 + ((2 * c + (quad >> 1)) ^ lx) * 8 + (quad & 1) * 4) =
          *(uint2*)pk.u;
    }
    __builtin_amdgcn_wave_barrier();   // order DS write -> DS read (wave-local)

#pragma unroll
    for (int t2 = 0; t2 < 2; ++t2) {
      bf16x8 pa = *(const bf16x8*)(Pw + l16 * 64 + ((t2 * 4 + quad) ^ lx) * 8);
      Lacc = mfma16(pa, ones, Lacc);   // row sums of P: lsum[q=quad*4+r]
#pragma unroll
      for (int c2 = 0; c2 < 4; ++c2) {
        bf16x8 vb = *(const bf16x8*)(Vs[cur] + (c2 * 16 + l16) * 64 +
                                     ((t2 * 4 + quad) ^ lx) * 8);
        O[c2] = mfma16(pa, vb, O[c2]);
      }
    }

    if (tile < 17) {   // stage next tile into the other buffer (safe: barrier t-1 passed)
      *(uint4*)(Ks[cur ^ 1] + loff0) = kr0;
      *(uint4*)(Ks[cur ^ 1] + loff1) = kr1;
      *(uint4*)(Vs[cur ^ 1] + loff0) = vr0;
      *(uint4*)(Vs[cur ^ 1] + loff1) = vr1;
    }
    __syncthreads();
  }

#pragma unroll
  for (int r = 0; r < 4; ++r) {
    float inv = 1.0f / Lacc[r];
#pragma unroll
    for (int c2 = 0; c2 < 4; ++c2)
      Aout[(size_t)(token0 + quad * 4 + r) * DMODEL + h * HD + c2 * 16 + l16] =
          f2bf(O[c2][r] * inv);
  }
}

// ---------------- launch ----------------
extern "C" void kernel_launch(void* const* d_in, const int* in_sizes, int n_in,
                              void* d_out, int out_size, void* d_ws, size_t ws_size,
                              hipStream_t stream) {
  const float* queries = (const float*)d_in[0];
  const float* keys    = (const float*)d_in[1];
  const float* values  = (const float*)d_in[2];
  const float* Wq = (const float*)d_in[3];
  const float* bq = (const float*)d_in[4];
  const float* Wk = (const float*)d_in[5];
  const float* bk = (const float*)d_in[6];
  const float* Wv = (const float*)d_in[7];
  const float* bv = (const float*)d_in[8];
  const float* Wo = (const float*)d_in[9];
  const float* bo = (const float*)d_in[10];
  const float* mk = (const float*)d_in[11];
  const float* mv = (const float*)d_in[12];

  unsigned short* ws = (unsigned short*)d_ws;
  unsigned short* Qin  = ws + OF_QIN;
  unsigned short* Kin  = ws + OF_KIN;
  unsigned short* Vin  = ws + OF_VIN;
  unsigned short* Wqt  = ws + OF_WQT;
  unsigned short* Wkt  = ws + OF_WKT;
  unsigned short* Wvt  = ws + OF_WVT;
  unsigned short* Wot  = ws + OF_WOT;
  unsigned short* Qbp  = ws + OF_QB;
  unsigned short* Kprp = ws + OF_KPR;
  unsigned short* Kmm  = ws + OF_KMEM;
  unsigned short* VtGp = ws + OF_VTG;
  unsigned short* Aoutp = ws + OF_AOUT;

  prep_all<<<8832, 256, 0, stream>>>(queries, keys, values, Wq, Wk, Wv, Wo, mk, mv,
                                     Qin, Kin, Vin, Wqt, Wkt, Wvt, Wot, Kmm, VtGp);

  proj_qkv<<<1536, 256, 0, stream>>>(Qin, Kin, Vin, Wqt, Wkt, Wvt, bq, bk, bv,
                                     Qbp, Kprp, VtGp);

  attn_kernel<<<1024, 256, 0, stream>>>(Qbp, Kprp, Kmm, VtGp, Aoutp);

  gemm_out<<<1024, 256, 0, stream>>>(Aoutp, Wot, bo, (float*)d_out);
}